// Round 3
// baseline (16187.392 us; speedup 1.0000x reference)
//
#include <hip/hip_runtime.h>
#include <stdint.h>

#define HD 128
#define EE 300000

// ---------------- weight pre-sum (WrSum per (layer,type), blSum) ----------------
struct WSumArgs {
  const float* Wr;   // [2][26][128][128]
  const float* bl;   // [2][26][128]
  float* WrSum;      // [2][10][128][128]
  float* blSum;      // [2][10][128]
  unsigned int mask[2][10];
};

__global__ __launch_bounds__(256) void wsum_kernel(WSumArgs a) {
  int lt  = blockIdx.x >> 6;      // /64
  int blk = blockIdx.x & 63;
  int layer = lt / 10, type = lt % 10;
  unsigned m = a.mask[layer][type];
  int idx = blk * 256 + threadIdx.x;   // 0..16383
  float s = 0.f;
  for (int r = 0; r < 26; ++r)
    if (m & (1u << r)) s += a.Wr[((size_t)(layer * 26 + r) << 14) + idx];
  a.WrSum[((size_t)(layer * 10 + type) << 14) + idx] = s;
  if (idx < HD) {
    float b = 0.f;
    for (int r = 0; r < 26; ++r)
      if (m & (1u << r)) b += a.bl[(size_t)(layer * 26 + r) * HD + idx];
    a.blSum[(size_t)(layer * 10 + type) * HD + idx] = b;
  }
}

// ---------------- degree count ----------------
struct DegArgs {
  const int* ei[13];
  float* deg;
  int degOff[26];
  int relList[26];
  int nrel;
};

__global__ __launch_bounds__(256) void deg_kernel(DegArgs a) {
  int i = blockIdx.x * 256 + threadIdx.x;
  if (i >= a.nrel * EE) return;
  int ri = i / EE;
  int e  = i - ri * EE;
  int r  = a.relList[ri];
  const int* ei = a.ei[r >> 1];
  int dst = (r & 1) ? ei[e] : ei[EE + e];
  unsafeAtomicAdd(&a.deg[a.degOff[r] + dst], 1.0f);
}

__global__ __launch_bounds__(256) void inv_kernel(float* d, int n) {
  int i = blockIdx.x * 256 + threadIdx.x;
  if (i < n) d[i] = 1.0f / fmaxf(d[i], 1.0f);
}

// ---------------- fp32 GEMM: C[M x 128] = A[M x 128] @ W[128 x 128] (+bias) ----------------
struct GemmArgs { const float* A; const float* W; const float* bias; float* C; int M; };

__global__ __launch_bounds__(256) void gemm128_kernel(GemmArgs g) {
  __shared__ float As[8][HD];  // k-major A panel
  __shared__ float Ws[8][HD];  // k-major W panel
  const int t = threadIdx.x;
  const int rowBase = blockIdx.x * HD;
  const int tr = t >> 4, tc = t & 15;       // 16x16 thread grid, 8x8 microtile
  const int lrow = t >> 1, lhalf = t & 1;   // A loader
  const int wkk = t >> 5, wc4 = t & 31;     // W loader

  float acc[8][8];
  #pragma unroll
  for (int i = 0; i < 8; ++i)
    #pragma unroll
    for (int j = 0; j < 8; ++j) acc[i][j] = 0.f;

  for (int k0 = 0; k0 < HD; k0 += 8) {
    float4 av = make_float4(0.f, 0.f, 0.f, 0.f);
    int grow = rowBase + lrow;
    if (grow < g.M) av = *(const float4*)(g.A + (size_t)grow * HD + k0 + (lhalf << 2));
    float4 wv = *(const float4*)(g.W + (size_t)(k0 + wkk) * HD + (wc4 << 2));
    __syncthreads();
    As[(lhalf << 2) + 0][lrow] = av.x;
    As[(lhalf << 2) + 1][lrow] = av.y;
    As[(lhalf << 2) + 2][lrow] = av.z;
    As[(lhalf << 2) + 3][lrow] = av.w;
    *(float4*)(&Ws[wkk][wc4 << 2]) = wv;
    __syncthreads();
    #pragma unroll
    for (int kk = 0; kk < 8; ++kk) {
      float4 a0 = *(const float4*)(&As[kk][tr << 3]);
      float4 a1 = *(const float4*)(&As[kk][(tr << 3) + 4]);
      float4 w0 = *(const float4*)(&Ws[kk][tc << 3]);
      float4 w1 = *(const float4*)(&Ws[kk][(tc << 3) + 4]);
      float ar[8] = {a0.x, a0.y, a0.z, a0.w, a1.x, a1.y, a1.z, a1.w};
      float wr[8] = {w0.x, w0.y, w0.z, w0.w, w1.x, w1.y, w1.z, w1.w};
      #pragma unroll
      for (int i = 0; i < 8; ++i)
        #pragma unroll
        for (int j = 0; j < 8; ++j)
          acc[i][j] = fmaf(ar[i], wr[j], acc[i][j]);
    }
  }

  float bsv[8] = {0.f, 0.f, 0.f, 0.f, 0.f, 0.f, 0.f, 0.f};
  if (g.bias) {
    float4 b0 = *(const float4*)(g.bias + (tc << 3));
    float4 b1 = *(const float4*)(g.bias + (tc << 3) + 4);
    bsv[0] = b0.x; bsv[1] = b0.y; bsv[2] = b0.z; bsv[3] = b0.w;
    bsv[4] = b1.x; bsv[5] = b1.y; bsv[6] = b1.z; bsv[7] = b1.w;
  }
  #pragma unroll
  for (int i = 0; i < 8; ++i) {
    int row = rowBase + (tr << 3) + i;
    if (row < g.M) {
      float4 o0 = make_float4(acc[i][0] + bsv[0], acc[i][1] + bsv[1],
                              acc[i][2] + bsv[2], acc[i][3] + bsv[3]);
      float4 o1 = make_float4(acc[i][4] + bsv[4], acc[i][5] + bsv[5],
                              acc[i][6] + bsv[6], acc[i][7] + bsv[7]);
      *(float4*)(g.C + (size_t)row * HD + (tc << 3)) = o0;
      *(float4*)(g.C + (size_t)row * HD + (tc << 3) + 4) = o1;
    }
  }
}

// ---------------- edge scatter: out[dst] += T[src] * invdeg[dst] ----------------
struct ScatArgs { const float* T; const int* ei; const float* invdeg; float* outp; int flip; };

__global__ __launch_bounds__(256) void scatter_kernel(ScatArgs s) {
  int i = blockIdx.x * 256 + threadIdx.x;
  int e = i >> 5;                 // 32 threads per edge
  if (e >= EE) return;
  int j = (i & 31) << 2;          // float4 chunk
  int a0 = s.ei[e], a1 = s.ei[EE + e];
  int src = s.flip ? a1 : a0;
  int dst = s.flip ? a0 : a1;
  float w = s.invdeg[dst];
  float4 v = *(const float4*)(s.T + (size_t)src * HD + j);
  float* o = s.outp + (size_t)dst * HD + j;
  unsafeAtomicAdd(o + 0, v.x * w);
  unsafeAtomicAdd(o + 1, v.y * w);
  unsafeAtomicAdd(o + 2, v.z * w);
  unsafeAtomicAdd(o + 3, v.w * w);
}

// ---------------- relu (in place, float4) ----------------
__global__ __launch_bounds__(256) void relu_kernel(float4* x, int n4) {
  int i = blockIdx.x * 256 + threadIdx.x;
  if (i < n4) {
    float4 v = x[i];
    v.x = fmaxf(v.x, 0.f); v.y = fmaxf(v.y, 0.f);
    v.z = fmaxf(v.z, 0.f); v.w = fmaxf(v.w, 0.f);
    x[i] = v;
  }
}

// ---------------- final: out[M x 64] = X[M x 128] @ W[128 x 64] + b ----------------
struct FinalArgs { const float* X; const float* W; const float* b; float* out; int M; };

__global__ __launch_bounds__(256) void final_kernel(FinalArgs f) {
  __shared__ float xs[512];      // 4 rows x 128
  int t = threadIdx.x;
  int row0 = blockIdx.x << 2;
  {
    int li = t << 1;
    int lrow = li >> 7;
    float2 v = make_float2(0.f, 0.f);
    if (row0 + lrow < f.M) v = *(const float2*)(f.X + (size_t)(row0 + lrow) * HD + (li & 127));
    *(float2*)(&xs[li]) = v;
  }
  __syncthreads();
  int r = t >> 6, c = t & 63;
  float acc = 0.f;
  const float* xrow = &xs[r << 7];
  #pragma unroll 8
  for (int k = 0; k < HD; ++k) acc = fmaf(xrow[k], f.W[k * 64 + c], acc);
  if (row0 + r < f.M) f.out[(size_t)(row0 + r) * 64 + c] = acc + f.b[c];
}

// ---------------- host ----------------
extern "C" void kernel_launch(void* const* d_in, const int* in_sizes, int n_in,
                              void* d_out, int out_size, void* d_ws, size_t ws_size,
                              hipStream_t stream) {
  static const int NODESN[10] = {50000, 2000, 80000, 10000, 2000, 150000, 120000, 100000, 60000, 40000};
  static const int FWD_S[13] = {0, 0, 0, 0, 0, 0, 6, 5, 5, 4, 4, 2, 2};
  static const int FWD_D[13] = {1, 2, 3, 4, 5, 6, 7, 6, 7, 5, 3, 8, 9};
  // layer-1 active relations (dst not in {reply=7, exercise=8, video=9})
  static const int ACT1[22] = {0,1,2,3,4,5,6,7,8,9,10,11,13,14,15,17,18,19,20,21,23,25};
  // layer-2 active relations (dst == course)
  static const int ACT2[6] = {1, 3, 5, 7, 9, 11};
  // A buffer holds types 0..6 (course..comment), row offsets:
  static const int AOFF[7] = {0, 50000, 52000, 132000, 142000, 144000, 294000};

  // workspace layout (floats)
  float* ws = (float*)d_ws;
  size_t offA   = 0;                                   // 414000 x 128
  size_t offB   = offA + (size_t)414000 * HD;          // 50000 x 128
  size_t offT   = offB + (size_t)50000 * HD;           // 150000 x 128 (max n_src)
  size_t offDeg = offT + (size_t)150000 * HD;          // 1,828,000
  size_t offWrS = offDeg + 1828000;                    // 2*10*16384
  size_t offBlS = offWrS + (size_t)2 * 10 * 16384;     // 2*10*128
  size_t needFloats = offBlS + (size_t)2 * 10 * HD;

  // Defensive: if the harness workspace is smaller than our layout, launch
  // nothing (clean absmax failure) instead of faulting the GPU.
  if (ws_size < needFloats * sizeof(float)) return;

  const float* x_in[10];
  for (int t = 0; t < 10; ++t) x_in[t] = (const float*)d_in[t];
  const int* ei[13];
  for (int k = 0; k < 13; ++k) ei[k] = (const int*)d_in[10 + k];
  const float* Wl   = (const float*)d_in[23];
  const float* bl   = (const float*)d_in[24];
  const float* Wr   = (const float*)d_in[25];
  const float* linW = (const float*)d_in[26];
  const float* linb = (const float*)d_in[27];
  float* out = (float*)d_out;

  auto relSrc = [&](int r) { int k = r >> 1; return (r & 1) ? FWD_D[k] : FWD_S[k]; };
  auto relDst = [&](int r) { int k = r >> 1; return (r & 1) ? FWD_S[k] : FWD_D[k]; };

  int degOff[26];
  {
    int acc = 0;
    for (int r = 0; r < 26; ++r) { degOff[r] = acc; acc += NODESN[relDst(r)]; }
  }

  // 1. zero deg
  hipMemsetAsync(ws + offDeg, 0, 1828000 * sizeof(float), stream);

  // 2. WrSum / blSum
  WSumArgs wa{};
  wa.Wr = Wr; wa.bl = bl; wa.WrSum = ws + offWrS; wa.blSum = ws + offBlS;
  for (int l = 0; l < 2; ++l)
    for (int t = 0; t < 10; ++t) wa.mask[l][t] = 0;
  for (int r = 0; r < 26; ++r) { int d = relDst(r); if (d <= 6) wa.mask[0][d] |= 1u << r; }
  for (int i = 0; i < 6; ++i) wa.mask[1][0] |= 1u << ACT2[i];
  wsum_kernel<<<1280, 256, 0, stream>>>(wa);

  // 3. deg + inv
  DegArgs da{};
  for (int k = 0; k < 13; ++k) da.ei[k] = ei[k];
  da.deg = ws + offDeg;
  for (int r = 0; r < 26; ++r) da.degOff[r] = degOff[r];
  for (int i = 0; i < 22; ++i) da.relList[i] = ACT1[i];
  da.nrel = 22;
  deg_kernel<<<(22 * EE + 255) / 256, 256, 0, stream>>>(da);
  inv_kernel<<<(1828000 + 255) / 256, 256, 0, stream>>>(ws + offDeg, 1828000);

  // 4. layer 1: init out = x @ WrSum + blSum for types 0..6
  for (int d = 0; d < 7; ++d) {
    GemmArgs g{x_in[d], ws + offWrS + (size_t)d * 16384, ws + offBlS + (size_t)d * HD,
               ws + offA + (size_t)AOFF[d] * HD, NODESN[d]};
    gemm128_kernel<<<(NODESN[d] + 127) / 128, 256, 0, stream>>>(g);
  }
  // layer 1: per relation T = x[s] @ Wl, then scatter into out[d]
  for (int i = 0; i < 22; ++i) {
    int r = ACT1[i];
    int s = relSrc(r), d = relDst(r);
    GemmArgs g{x_in[s], Wl + ((size_t)r << 14), nullptr, ws + offT, NODESN[s]};
    gemm128_kernel<<<(NODESN[s] + 127) / 128, 256, 0, stream>>>(g);
    ScatArgs sc{ws + offT, ei[r >> 1], ws + offDeg + degOff[r],
                ws + offA + (size_t)AOFF[d] * HD, r & 1};
    scatter_kernel<<<EE * 32 / 256, 256, 0, stream>>>(sc);
  }
  relu_kernel<<<(13248000 + 255) / 256, 256, 0, stream>>>((float4*)(ws + offA), 13248000);

  // 5. layer 2 (course only)
  {
    GemmArgs g{ws + offA, ws + offWrS + (size_t)10 * 16384, ws + offBlS + (size_t)10 * HD,
               ws + offB, 50000};
    gemm128_kernel<<<(50000 + 127) / 128, 256, 0, stream>>>(g);
  }
  for (int i = 0; i < 6; ++i) {
    int r = ACT2[i];
    int s = relSrc(r);
    GemmArgs g{ws + offA + (size_t)AOFF[s] * HD, Wl + ((size_t)(26 + r) << 14), nullptr,
               ws + offT, NODESN[s]};
    gemm128_kernel<<<(NODESN[s] + 127) / 128, 256, 0, stream>>>(g);
    ScatArgs sc{ws + offT, ei[r >> 1], ws + offDeg + degOff[r], ws + offB, r & 1};
    scatter_kernel<<<EE * 32 / 256, 256, 0, stream>>>(sc);
  }
  relu_kernel<<<(1600000 + 255) / 256, 256, 0, stream>>>((float4*)(ws + offB), 1600000);

  // 6. final linear
  FinalArgs fa{ws + offB, linW, linb, out, 50000};
  final_kernel<<<12500, 256, 0, stream>>>(fa);
}

// Round 5
// 3964.039 us; speedup vs baseline: 4.0836x; 4.0836x over previous
//
#include <hip/hip_runtime.h>
#include <stdint.h>

#define HD 128
#define EE 300000

// ---------------- weight pre-sum (WrSum per (layer,type), blSum) ----------------
struct WSumArgs {
  const float* Wr;   // [2][26][128][128]
  const float* bl;   // [2][26][128]
  float* WrSum;      // [2][10][128][128]
  float* blSum;      // [2][10][128]
  unsigned int mask[2][10];
};

__global__ __launch_bounds__(256) void wsum_kernel(WSumArgs a) {
  int lt  = blockIdx.x >> 6;      // /64
  int blk = blockIdx.x & 63;
  int layer = lt / 10, type = lt % 10;
  unsigned m = a.mask[layer][type];
  int idx = blk * 256 + threadIdx.x;   // 0..16383
  float s = 0.f;
  for (int r = 0; r < 26; ++r)
    if (m & (1u << r)) s += a.Wr[((size_t)(layer * 26 + r) << 14) + idx];
  a.WrSum[((size_t)(layer * 10 + type) << 14) + idx] = s;
  if (idx < HD) {
    float b = 0.f;
    for (int r = 0; r < 26; ++r)
      if (m & (1u << r)) b += a.bl[(size_t)(layer * 26 + r) * HD + idx];
    a.blSum[(size_t)(layer * 10 + type) * HD + idx] = b;
  }
}

// ---------------- transient 2-relation CSR build: histogram, scan, fill ----------------
struct Build2Args {
  const int* ei0; const int* ei1;   // edge arrays [2*EE] for the two relations
  int flip0, flip1;                 // reverse-relation flags
  int seg1;                         // cnt offset of relation 1 (= n_dst of relation 0)
  int* cnt;                         // [seg1 + n_dst1] histogram / cursor
  int* col;                         // [2*EE] column (src) array
};

__global__ __launch_bounds__(256) void hist2_kernel(Build2Args a) {
  int i = blockIdx.x * 256 + threadIdx.x;
  if (i >= 2 * EE) return;
  int ri = i / EE;
  int e  = i - ri * EE;
  const int* ei = ri ? a.ei1 : a.ei0;
  int flip = ri ? a.flip1 : a.flip0;
  int dst = flip ? ei[e] : ei[EE + e];
  atomicAdd(&a.cnt[(ri ? a.seg1 : 0) + dst], 1);
}

__global__ __launch_bounds__(256) void fill2_kernel(Build2Args a) {
  int i = blockIdx.x * 256 + threadIdx.x;
  if (i >= 2 * EE) return;
  int ri = i / EE;
  int e  = i - ri * EE;
  const int* ei = ri ? a.ei1 : a.ei0;
  int flip = ri ? a.flip1 : a.flip0;
  int src = flip ? ei[EE + e] : ei[e];
  int dst = flip ? ei[e] : ei[EE + e];
  int pos = atomicAdd(&a.cnt[(ri ? a.seg1 : 0) + dst], 1);
  a.col[pos] = src;
}

// block-level exclusive scan: 256 threads x 8 elements = 2048 per block
__global__ __launch_bounds__(256) void scan_blk(const int* cnt, int* rp, int* bsum, int n) {
  __shared__ int sh[256];
  int t = threadIdx.x;
  int base = blockIdx.x * 2048 + t * 8;
  int v[8]; int s = 0;
  #pragma unroll
  for (int j = 0; j < 8; ++j) { int idx = base + j; v[j] = (idx < n) ? cnt[idx] : 0; s += v[j]; }
  sh[t] = s; __syncthreads();
  for (int d = 1; d < 256; d <<= 1) {
    int x = (t >= d) ? sh[t - d] : 0;
    __syncthreads();
    sh[t] += x;
    __syncthreads();
  }
  int excl = sh[t] - s;
  if (t == 255) bsum[blockIdx.x] = sh[255];
  int run = excl;
  #pragma unroll
  for (int j = 0; j < 8; ++j) { int idx = base + j; if (idx < n) rp[idx] = run; run += v[j]; }
}

// single-block exclusive scan of block sums (nb <= 1024)
__global__ __launch_bounds__(1024) void scan_top(int* bsum, int nb) {
  __shared__ int sh[1024];
  int t = threadIdx.x;
  int s = (t < nb) ? bsum[t] : 0;
  sh[t] = s; __syncthreads();
  for (int d = 1; d < 1024; d <<= 1) {
    int x = (t >= d) ? sh[t - d] : 0;
    __syncthreads();
    sh[t] += x;
    __syncthreads();
  }
  if (t < nb) bsum[t] = sh[t] - s;   // exclusive
}

// add block offsets; write rowptr and seed cursor (cnt array reused as cursor)
__global__ __launch_bounds__(256) void scan_add(int* rp, int* cur, const int* bsum, int n, int total) {
  int i = blockIdx.x * 256 + threadIdx.x;
  if (i < n) { int v = rp[i] + bsum[i >> 11]; rp[i] = v; cur[i] = v; }
  if (i == 0) rp[n] = total;
}

// ---------------- fp32 GEMM: C[M x 128] = A[M x 128] @ W[128 x 128] (+bias) ----------------
struct GemmArgs { const float* A; const float* W; const float* bias; float* C; int M; };

__global__ __launch_bounds__(256) void gemm128_kernel(GemmArgs g) {
  __shared__ float As[8][HD];  // k-major A panel
  __shared__ float Ws[8][HD];  // k-major W panel
  const int t = threadIdx.x;
  const int rowBase = blockIdx.x * HD;
  const int tr = t >> 4, tc = t & 15;       // 16x16 thread grid, 8x8 microtile
  const int lrow = t >> 1, lhalf = t & 1;   // A loader
  const int wkk = t >> 5, wc4 = t & 31;     // W loader

  float acc[8][8];
  #pragma unroll
  for (int i = 0; i < 8; ++i)
    #pragma unroll
    for (int j = 0; j < 8; ++j) acc[i][j] = 0.f;

  for (int k0 = 0; k0 < HD; k0 += 8) {
    float4 av = make_float4(0.f, 0.f, 0.f, 0.f);
    int grow = rowBase + lrow;
    if (grow < g.M) av = *(const float4*)(g.A + (size_t)grow * HD + k0 + (lhalf << 2));
    float4 wv = *(const float4*)(g.W + (size_t)(k0 + wkk) * HD + (wc4 << 2));
    __syncthreads();
    As[(lhalf << 2) + 0][lrow] = av.x;
    As[(lhalf << 2) + 1][lrow] = av.y;
    As[(lhalf << 2) + 2][lrow] = av.z;
    As[(lhalf << 2) + 3][lrow] = av.w;
    *(float4*)(&Ws[wkk][wc4 << 2]) = wv;
    __syncthreads();
    #pragma unroll
    for (int kk = 0; kk < 8; ++kk) {
      float4 a0 = *(const float4*)(&As[kk][tr << 3]);
      float4 a1 = *(const float4*)(&As[kk][(tr << 3) + 4]);
      float4 w0 = *(const float4*)(&Ws[kk][tc << 3]);
      float4 w1 = *(const float4*)(&Ws[kk][(tc << 3) + 4]);
      float ar[8] = {a0.x, a0.y, a0.z, a0.w, a1.x, a1.y, a1.z, a1.w};
      float wr[8] = {w0.x, w0.y, w0.z, w0.w, w1.x, w1.y, w1.z, w1.w};
      #pragma unroll
      for (int i = 0; i < 8; ++i)
        #pragma unroll
        for (int j = 0; j < 8; ++j)
          acc[i][j] = fmaf(ar[i], wr[j], acc[i][j]);
    }
  }

  float bsv[8] = {0.f, 0.f, 0.f, 0.f, 0.f, 0.f, 0.f, 0.f};
  if (g.bias) {
    float4 b0 = *(const float4*)(g.bias + (tc << 3));
    float4 b1 = *(const float4*)(g.bias + (tc << 3) + 4);
    bsv[0] = b0.x; bsv[1] = b0.y; bsv[2] = b0.z; bsv[3] = b0.w;
    bsv[4] = b1.x; bsv[5] = b1.y; bsv[6] = b1.z; bsv[7] = b1.w;
  }
  #pragma unroll
  for (int i = 0; i < 8; ++i) {
    int row = rowBase + (tr << 3) + i;
    if (row < g.M) {
      float4 o0 = make_float4(acc[i][0] + bsv[0], acc[i][1] + bsv[1],
                              acc[i][2] + bsv[2], acc[i][3] + bsv[3]);
      float4 o1 = make_float4(acc[i][4] + bsv[4], acc[i][5] + bsv[5],
                              acc[i][6] + bsv[6], acc[i][7] + bsv[7]);
      *(float4*)(g.C + (size_t)row * HD + (tc << 3)) = o0;
      *(float4*)(g.C + (size_t)row * HD + (tc << 3) + 4) = o1;
    }
  }
}

// ---------------- CSR gather: out[row] += mean_{src in row} T[src]  (one wave per row) ----------------
struct GatArgs { const float* T; const int* rp; const int* gcol; float* outp; int n; };

__global__ __launch_bounds__(256) void gather_kernel(GatArgs g) {
  int wid  = (blockIdx.x * 256 + threadIdx.x) >> 6;
  int lane = threadIdx.x & 63;
  if (wid >= g.n) return;
  int s = g.rp[wid], e = g.rp[wid + 1];
  if (s == e) return;
  int c = lane << 1;
  float2 acc = make_float2(0.f, 0.f);
  int i = s;
  for (; i + 1 < e; i += 2) {
    int s0 = g.gcol[i], s1 = g.gcol[i + 1];
    float2 v0 = *(const float2*)(g.T + (size_t)s0 * HD + c);
    float2 v1 = *(const float2*)(g.T + (size_t)s1 * HD + c);
    acc.x += v0.x + v1.x;
    acc.y += v0.y + v1.y;
  }
  if (i < e) {
    int s0 = g.gcol[i];
    float2 v0 = *(const float2*)(g.T + (size_t)s0 * HD + c);
    acc.x += v0.x; acc.y += v0.y;
  }
  float inv = 1.0f / (float)(e - s);
  float2* o = (float2*)(g.outp + (size_t)wid * HD + c);
  float2 cur = *o;
  cur.x += acc.x * inv;
  cur.y += acc.y * inv;
  *o = cur;
}

// ---------------- relu (in place, float4) ----------------
__global__ __launch_bounds__(256) void relu_kernel(float4* x, int n4) {
  int i = blockIdx.x * 256 + threadIdx.x;
  if (i < n4) {
    float4 v = x[i];
    v.x = fmaxf(v.x, 0.f); v.y = fmaxf(v.y, 0.f);
    v.z = fmaxf(v.z, 0.f); v.w = fmaxf(v.w, 0.f);
    x[i] = v;
  }
}

// ---------------- final: out[M x 64] = X[M x 128] @ W[128 x 64] + b ----------------
struct FinalArgs { const float* X; const float* W; const float* b; float* out; int M; };

__global__ __launch_bounds__(256) void final_kernel(FinalArgs f) {
  __shared__ float xs[512];      // 4 rows x 128
  int t = threadIdx.x;
  int row0 = blockIdx.x << 2;
  {
    int li = t << 1;
    int lrow = li >> 7;
    float2 v = make_float2(0.f, 0.f);
    if (row0 + lrow < f.M) v = *(const float2*)(f.X + (size_t)(row0 + lrow) * HD + (li & 127));
    *(float2*)(&xs[li]) = v;
  }
  __syncthreads();
  int r = t >> 6, c = t & 63;
  float acc = 0.f;
  const float* xrow = &xs[r << 7];
  #pragma unroll 8
  for (int k = 0; k < HD; ++k) acc = fmaf(xrow[k], f.W[k * 64 + c], acc);
  if (row0 + r < f.M) f.out[(size_t)(row0 + r) * 64 + c] = acc + f.b[c];
}

// ---------------- host ----------------
extern "C" void kernel_launch(void* const* d_in, const int* in_sizes, int n_in,
                              void* d_out, int out_size, void* d_ws, size_t ws_size,
                              hipStream_t stream) {
  static const int NODESN[10] = {50000, 2000, 80000, 10000, 2000, 150000, 120000, 100000, 60000, 40000};
  static const int FWD_S[13] = {0, 0, 0, 0, 0, 0, 6, 5, 5, 4, 4, 2, 2};
  static const int FWD_D[13] = {1, 2, 3, 4, 5, 6, 7, 6, 7, 5, 3, 8, 9};
  // layer-1 active relations (dst not in {reply=7, exercise=8, video=9}), processed in pairs
  static const int ACT1[22] = {0,1,2,3,4,5,6,7,8,9,10,11,13,14,15,17,18,19,20,21,23,25};
  // layer-2 active relations (dst == course)
  static const int ACT2[6] = {1, 3, 5, 7, 9, 11};
  // A buffer holds types 0..6 (course..comment), row offsets:
  static const int AOFF[7] = {0, 50000, 52000, 132000, 142000, 144000, 294000};

  // workspace layout (float-granular offsets; int regions cast)
  // A 212.0MB + B 25.6MB + T 76.8MB + scratch 4.8MB + weights 1.3MB = 320.5MB
  // (must stay <= round-3's 323.0MB, which is known to fit ws_size)
  float* ws = (float*)d_ws;
  size_t offA   = 0;                                   // 414000 x 128 f32
  size_t offB   = offA + (size_t)414000 * HD;          // 50000 x 128 f32
  size_t offT   = offB + (size_t)50000 * HD;           // 150000 x 128 f32
  size_t offCnt = offT + (size_t)150000 * HD;          // 300032 ints (2-rel histogram/cursor)
  size_t offRp  = offCnt + 300032;                     // 300034 ints (2-rel rowptr)
  size_t offCol = offRp + 300034;                      // 600000 ints (2-rel columns)
  size_t offBs  = offCol + 600000;                     // 1024 ints (scan block sums)
  size_t offWrS = offBs + 1024;                        // 2*10*16384 f32
  size_t offBlS = offWrS + (size_t)2 * 10 * 16384;     // 2*10*128 f32
  size_t needFloats = offBlS + (size_t)2 * 10 * HD;
  if (ws_size < needFloats * sizeof(float)) return;    // clean fail instead of faulting

  const float* x_in[10];
  for (int t = 0; t < 10; ++t) x_in[t] = (const float*)d_in[t];
  const int* ei[13];
  for (int k = 0; k < 13; ++k) ei[k] = (const int*)d_in[10 + k];
  const float* Wl   = (const float*)d_in[23];
  const float* bl   = (const float*)d_in[24];
  const float* Wr   = (const float*)d_in[25];
  const float* linW = (const float*)d_in[26];
  const float* linb = (const float*)d_in[27];
  float* out = (float*)d_out;

  int* cnt = (int*)(ws + offCnt);
  int* rp  = (int*)(ws + offRp);
  int* col = (int*)(ws + offCol);
  int* bs  = (int*)(ws + offBs);

  auto relSrc = [&](int r) { int k = r >> 1; return (r & 1) ? FWD_D[k] : FWD_S[k]; };
  auto relDst = [&](int r) { int k = r >> 1; return (r & 1) ? FWD_S[k] : FWD_D[k]; };

  // 1. WrSum / blSum
  WSumArgs wa{};
  wa.Wr = Wr; wa.bl = bl; wa.WrSum = ws + offWrS; wa.blSum = ws + offBlS;
  for (int l = 0; l < 2; ++l)
    for (int t = 0; t < 10; ++t) wa.mask[l][t] = 0;
  for (int r = 0; r < 26; ++r) { int d = relDst(r); if (d <= 6) wa.mask[0][d] |= 1u << r; }
  for (int i = 0; i < 6; ++i) wa.mask[1][0] |= 1u << ACT2[i];
  wsum_kernel<<<1280, 256, 0, stream>>>(wa);

  // builds the transient CSR for a pair of relations (rA, rB)
  auto buildPair = [&](int rA, int rB) {
    int nA = NODESN[relDst(rA)], nB = NODESN[relDst(rB)];
    int n = nA + nB;
    hipMemsetAsync(cnt, 0, (size_t)n * sizeof(int), stream);
    Build2Args ba{ei[rA >> 1], ei[rB >> 1], rA & 1, rB & 1, nA, cnt, col};
    hist2_kernel<<<(2 * EE + 255) / 256, 256, 0, stream>>>(ba);
    int nblk = (n + 2047) / 2048;   // <= 147
    scan_blk<<<nblk, 256, 0, stream>>>(cnt, rp, bs, n);
    scan_top<<<1, 1024, 0, stream>>>(bs, nblk);
    scan_add<<<(n + 255) / 256, 256, 0, stream>>>(rp, cnt, bs, n, 2 * EE);
    fill2_kernel<<<(2 * EE + 255) / 256, 256, 0, stream>>>(ba);
  };
  // transform + gather for one relation (rp segment at segOff)
  auto transGather = [&](int r, int segOff, const float* xsrc, const float* Wmat, float* outd) {
    int s = relSrc(r), d = relDst(r);
    GemmArgs g{xsrc, Wmat, nullptr, ws + offT, NODESN[s]};
    gemm128_kernel<<<(NODESN[s] + 127) / 128, 256, 0, stream>>>(g);
    GatArgs ga{ws + offT, rp + segOff, col, outd, NODESN[d]};
    gather_kernel<<<(NODESN[d] + 3) / 4, 256, 0, stream>>>(ga);
  };

  // 2. layer 1: init out = x @ WrSum + blSum for types 0..6
  for (int d = 0; d < 7; ++d) {
    GemmArgs g{x_in[d], ws + offWrS + (size_t)d * 16384, ws + offBlS + (size_t)d * HD,
               ws + offA + (size_t)AOFF[d] * HD, NODESN[d]};
    gemm128_kernel<<<(NODESN[d] + 127) / 128, 256, 0, stream>>>(g);
  }
  // layer 1: pairs of relations — build CSR, then transform+gather each
  for (int p = 0; p < 11; ++p) {
    int rA = ACT1[2 * p], rB = ACT1[2 * p + 1];
    buildPair(rA, rB);
    transGather(rA, 0, x_in[relSrc(rA)], Wl + ((size_t)rA << 14),
                ws + offA + (size_t)AOFF[relDst(rA)] * HD);
    transGather(rB, NODESN[relDst(rA)], x_in[relSrc(rB)], Wl + ((size_t)rB << 14),
                ws + offA + (size_t)AOFF[relDst(rB)] * HD);
  }
  relu_kernel<<<(13248000 + 255) / 256, 256, 0, stream>>>((float4*)(ws + offA), 13248000);

  // 3. layer 2 (course only)
  {
    GemmArgs g{ws + offA, ws + offWrS + (size_t)10 * 16384, ws + offBlS + (size_t)10 * HD,
               ws + offB, 50000};
    gemm128_kernel<<<(50000 + 127) / 128, 256, 0, stream>>>(g);
  }
  for (int p = 0; p < 3; ++p) {
    int rA = ACT2[2 * p], rB = ACT2[2 * p + 1];
    buildPair(rA, rB);
    transGather(rA, 0, ws + offA + (size_t)AOFF[relSrc(rA)] * HD,
                Wl + ((size_t)(26 + rA) << 14), ws + offB);
    transGather(rB, NODESN[relDst(rA)], ws + offA + (size_t)AOFF[relSrc(rB)] * HD,
                Wl + ((size_t)(26 + rB) << 14), ws + offB);
  }
  relu_kernel<<<(1600000 + 255) / 256, 256, 0, stream>>>((float4*)(ws + offB), 1600000);

  // 4. final linear
  FinalArgs fa{ws + offB, linW, linb, out, 50000};
  final_kernel<<<12500, 256, 0, stream>>>(fa);
}

// Round 7
// 3099.786 us; speedup vs baseline: 5.2221x; 1.2788x over previous
//
#include <hip/hip_runtime.h>
#include <stdint.h>

#define HD 128
#define EE 300000

typedef __attribute__((ext_vector_type(8))) short bf16x8;
typedef __attribute__((ext_vector_type(4))) float f32x4;

static __device__ __forceinline__ unsigned short f2bf(float x) {
  union { float f; unsigned u; } v; v.f = x;
  unsigned r = v.u + 0x7FFFu + ((v.u >> 16) & 1u);
  return (unsigned short)(r >> 16);
}
static __device__ __forceinline__ float bf2f(unsigned short h) {
  union { unsigned u; float f; } v; v.u = ((unsigned)h) << 16;
  return v.f;
}

// ---------------- weight pre-sum (WrSum per (layer,type), blSum) ----------------
struct WSumArgs {
  const float* Wr;   // [2][26][128][128]
  const float* bl;   // [2][26][128]
  float* WrSum;      // [2][10][128][128]
  float* blSum;      // [2][10][128]
  unsigned int mask[2][10];
};

__global__ __launch_bounds__(256) void wsum_kernel(WSumArgs a) {
  int lt  = blockIdx.x >> 6;
  int blk = blockIdx.x & 63;
  int layer = lt / 10, type = lt % 10;
  unsigned m = a.mask[layer][type];
  int idx = blk * 256 + threadIdx.x;   // 0..16383
  float s = 0.f;
  for (int r = 0; r < 26; ++r)
    if (m & (1u << r)) s += a.Wr[((size_t)(layer * 26 + r) << 14) + idx];
  a.WrSum[((size_t)(layer * 10 + type) << 14) + idx] = s;
  if (idx < HD) {
    float b = 0.f;
    for (int r = 0; r < 26; ++r)
      if (m & (1u << r)) b += a.bl[(size_t)(layer * 26 + r) * HD + idx];
    a.blSum[(size_t)(layer * 10 + type) * HD + idx] = b;
  }
}

// ---------------- weight transpose+bf16 prep: wt[m][n][k] = bf16(src[m][k][n]) ----------------
struct WtPrepArgs {
  const float* Wl;     // [52][128][128]
  const float* WrSum;  // [20][128][128]
  unsigned short* wt;  // [36][128][128] (n-major, k contiguous)
  int code[36];        // <100: Wl flat index; >=100: WrSum flat index - 100
};

__global__ __launch_bounds__(256) void wtprep_kernel(WtPrepArgs a) {
  int m = blockIdx.x >> 4;
  int chunk = blockIdx.x & 15;
  int idx = chunk * 256 + threadIdx.x;   // float4 index 0..4095
  int c = a.code[m];
  const float* src = (c < 100) ? a.Wl + ((size_t)c << 14)
                               : a.WrSum + ((size_t)(c - 100) << 14);
  int k = idx >> 5, n0 = (idx & 31) << 2;
  float4 v = *(const float4*)(src + (size_t)k * HD + n0);
  unsigned short* d = a.wt + ((size_t)m << 14);
  d[(size_t)(n0 + 0) * HD + k] = f2bf(v.x);
  d[(size_t)(n0 + 1) * HD + k] = f2bf(v.y);
  d[(size_t)(n0 + 2) * HD + k] = f2bf(v.z);
  d[(size_t)(n0 + 3) * HD + k] = f2bf(v.w);
}

// ---------------- transient 2-relation CSR build: histogram, scan, fill ----------------
struct Build2Args {
  const int* ei0; const int* ei1;
  int flip0, flip1;
  int seg1;
  int* cnt;
  int* col;
};

__global__ __launch_bounds__(256) void hist2_kernel(Build2Args a) {
  int i = blockIdx.x * 256 + threadIdx.x;
  if (i >= 2 * EE) return;
  int ri = i / EE;
  int e  = i - ri * EE;
  const int* ei = ri ? a.ei1 : a.ei0;
  int flip = ri ? a.flip1 : a.flip0;
  int dst = flip ? ei[e] : ei[EE + e];
  atomicAdd(&a.cnt[(ri ? a.seg1 : 0) + dst], 1);
}

__global__ __launch_bounds__(256) void fill2_kernel(Build2Args a) {
  int i = blockIdx.x * 256 + threadIdx.x;
  if (i >= 2 * EE) return;
  int ri = i / EE;
  int e  = i - ri * EE;
  const int* ei = ri ? a.ei1 : a.ei0;
  int flip = ri ? a.flip1 : a.flip0;
  int src = flip ? ei[EE + e] : ei[e];
  int dst = flip ? ei[e] : ei[EE + e];
  int pos = atomicAdd(&a.cnt[(ri ? a.seg1 : 0) + dst], 1);
  a.col[pos] = src;
}

__global__ __launch_bounds__(256) void scan_blk(const int* cnt, int* rp, int* bsum, int n) {
  __shared__ int sh[256];
  int t = threadIdx.x;
  int base = blockIdx.x * 2048 + t * 8;
  int v[8]; int s = 0;
  #pragma unroll
  for (int j = 0; j < 8; ++j) { int idx = base + j; v[j] = (idx < n) ? cnt[idx] : 0; s += v[j]; }
  sh[t] = s; __syncthreads();
  for (int d = 1; d < 256; d <<= 1) {
    int x = (t >= d) ? sh[t - d] : 0;
    __syncthreads();
    sh[t] += x;
    __syncthreads();
  }
  int excl = sh[t] - s;
  if (t == 255) bsum[blockIdx.x] = sh[255];
  int run = excl;
  #pragma unroll
  for (int j = 0; j < 8; ++j) { int idx = base + j; if (idx < n) rp[idx] = run; run += v[j]; }
}

__global__ __launch_bounds__(1024) void scan_top(int* bsum, int nb) {
  __shared__ int sh[1024];
  int t = threadIdx.x;
  int s = (t < nb) ? bsum[t] : 0;
  sh[t] = s; __syncthreads();
  for (int d = 1; d < 1024; d <<= 1) {
    int x = (t >= d) ? sh[t - d] : 0;
    __syncthreads();
    sh[t] += x;
    __syncthreads();
  }
  if (t < nb) bsum[t] = sh[t] - s;
}

__global__ __launch_bounds__(256) void scan_add(int* rp, int* cur, const int* bsum, int n, int total) {
  int i = blockIdx.x * 256 + threadIdx.x;
  if (i < n) { int v = rp[i] + bsum[i >> 11]; rp[i] = v; cur[i] = v; }
  if (i == 0) rp[n] = total;
}

// ---------------- bf16 MFMA GEMM: C[M x 128] = A[M x 128] @ W[128 x 128] (+bias) ----------------
// A: fp32 row-major (converted to bf16 in staging). Wt: bf16 [n][k] (pre-transposed).
// C: fp32 or bf16 per outBf16. MFMA 16x16x32, fp32 accumulation.
struct MGemmArgs { const float* A; const unsigned short* Wt; const float* bias; void* C; int M; int outBf16; };

__global__ __launch_bounds__(256) void mgemm_kernel(MGemmArgs g) {
  __shared__ unsigned short As[64 * HD];   // [r][k] bf16, byte ^ ((r&7)<<4)
  __shared__ unsigned short Wsm[HD * HD];  // [n][k] bf16, byte ^ ((n&7)<<4)
  const int t = threadIdx.x;
  const int rowBase = blockIdx.x * 64;

  // stage A: 2048 float4 loads -> bf16 swizzled LDS
  #pragma unroll
  for (int it = 0; it < 8; ++it) {
    int f4 = t + it * 256;
    int flat = f4 << 2;
    int r = flat >> 7;
    int gr = rowBase + r; if (gr >= g.M) gr = g.M - 1;
    float4 v = *(const float4*)(g.A + (size_t)gr * HD + (flat & 127));
    ushort4 h;
    h.x = f2bf(v.x); h.y = f2bf(v.y); h.z = f2bf(v.z); h.w = f2bf(v.w);
    *(ushort4*)((char*)As + ((flat << 1) ^ ((r & 7) << 4))) = h;
  }
  // stage W: 4096 ushort4 copies -> swizzled LDS
  #pragma unroll
  for (int it = 0; it < 16; ++it) {
    int i4 = t + it * 256;
    int byteoff = i4 << 3;
    int n = i4 >> 5;
    ushort4 w = *(const ushort4*)((const char*)g.Wt + byteoff);
    *(ushort4*)((char*)Wsm + (byteoff ^ ((n & 7) << 4))) = w;
  }
  __syncthreads();

  const int wv = t >> 6;        // wave id: rows [wv*16, wv*16+16)
  const int lane = t & 63;
  const int lr = lane & 15;     // A row-in-tile / B col-in-tile
  const int lk = lane >> 4;     // k-group (8 elems each)

  bf16x8 afr[4];
  #pragma unroll
  for (int kc = 0; kc < 4; ++kc) {
    int r = wv * 16 + lr;
    int byte = r * 256 + kc * 64 + lk * 16;
    afr[kc] = *(const bf16x8*)((char*)As + (byte ^ ((r & 7) << 4)));
  }

  f32x4 acc[8];
  #pragma unroll
  for (int nt = 0; nt < 8; ++nt) acc[nt] = (f32x4){0.f, 0.f, 0.f, 0.f};

  #pragma unroll
  for (int nt = 0; nt < 8; ++nt) {
    int n = nt * 16 + lr;
    int nbyte = n * 256 + lk * 16;
    int nswz = (n & 7) << 4;
    #pragma unroll
    for (int kc = 0; kc < 4; ++kc) {
      bf16x8 bfr = *(const bf16x8*)((char*)Wsm + ((nbyte + kc * 64) ^ nswz));
      acc[nt] = __builtin_amdgcn_mfma_f32_16x16x32_bf16(afr[kc], bfr, acc[nt], 0, 0, 0);
    }
  }

  // epilogue: D row = wv*16 + lk*4 + q, col = nt*16 + lr
  #pragma unroll
  for (int nt = 0; nt < 8; ++nt) {
    int col = nt * 16 + lr;
    float bv = g.bias ? g.bias[col] : 0.f;
    #pragma unroll
    for (int q = 0; q < 4; ++q) {
      int grow = rowBase + wv * 16 + lk * 4 + q;
      if (grow < g.M) {
        float val = acc[nt][q] + bv;
        if (g.outBf16) ((unsigned short*)g.C)[(size_t)grow * HD + col] = f2bf(val);
        else           ((float*)g.C)[(size_t)grow * HD + col] = val;
      }
    }
  }
}

// ---------------- CSR gather (bf16 T): out[row] += mean_{src} T[src] ----------------
struct GatArgs { const unsigned short* T; const int* rp; const int* gcol; float* outp; int n; };

__global__ __launch_bounds__(256) void gather_kernel(GatArgs g) {
  int wid  = (blockIdx.x * 256 + threadIdx.x) >> 6;
  int lane = threadIdx.x & 63;
  if (wid >= g.n) return;
  int s = g.rp[wid], e = g.rp[wid + 1];
  if (s == e) return;
  int h = lane >> 5, cl = lane & 31;   // half-wave h processes neighbors s+h, s+h+2, ...
  float a0 = 0.f, a1 = 0.f, a2 = 0.f, a3 = 0.f;
  for (int i = s + h; i < e; i += 2) {
    int src = g.gcol[i];
    ushort4 v = *(const ushort4*)(g.T + (size_t)src * HD + (cl << 2));
    a0 += bf2f(v.x); a1 += bf2f(v.y); a2 += bf2f(v.z); a3 += bf2f(v.w);
  }
  a0 += __shfl_xor(a0, 32); a1 += __shfl_xor(a1, 32);
  a2 += __shfl_xor(a2, 32); a3 += __shfl_xor(a3, 32);
  if (h == 0) {
    float inv = 1.0f / (float)(e - s);
    float4* o = (float4*)(g.outp + (size_t)wid * HD + (cl << 2));
    float4 c = *o;
    c.x += a0 * inv; c.y += a1 * inv; c.z += a2 * inv; c.w += a3 * inv;
    *o = c;
  }
}

// ---------------- relu (in place, float4) ----------------
__global__ __launch_bounds__(256) void relu_kernel(float4* x, int n4) {
  int i = blockIdx.x * 256 + threadIdx.x;
  if (i < n4) {
    float4 v = x[i];
    v.x = fmaxf(v.x, 0.f); v.y = fmaxf(v.y, 0.f);
    v.z = fmaxf(v.z, 0.f); v.w = fmaxf(v.w, 0.f);
    x[i] = v;
  }
}

// ---------------- final: out[M x 64] = X[M x 128] @ W[128 x 64] + b ----------------
struct FinalArgs { const float* X; const float* W; const float* b; float* out; int M; };

__global__ __launch_bounds__(256) void final_kernel(FinalArgs f) {
  __shared__ float xs[512];
  int t = threadIdx.x;
  int row0 = blockIdx.x << 2;
  {
    int li = t << 1;
    int lrow = li >> 7;
    float2 v = make_float2(0.f, 0.f);
    if (row0 + lrow < f.M) v = *(const float2*)(f.X + (size_t)(row0 + lrow) * HD + (li & 127));
    *(float2*)(&xs[li]) = v;
  }
  __syncthreads();
  int r = t >> 6, c = t & 63;
  float acc = 0.f;
  const float* xrow = &xs[r << 7];
  #pragma unroll 8
  for (int k = 0; k < HD; ++k) acc = fmaf(xrow[k], f.W[k * 64 + c], acc);
  if (row0 + r < f.M) f.out[(size_t)(row0 + r) * 64 + c] = acc + f.b[c];
}

// ---------------- host ----------------
extern "C" void kernel_launch(void* const* d_in, const int* in_sizes, int n_in,
                              void* d_out, int out_size, void* d_ws, size_t ws_size,
                              hipStream_t stream) {
  static const int NODESN[10] = {50000, 2000, 80000, 10000, 2000, 150000, 120000, 100000, 60000, 40000};
  static const int FWD_S[13] = {0, 0, 0, 0, 0, 0, 6, 5, 5, 4, 4, 2, 2};
  static const int FWD_D[13] = {1, 2, 3, 4, 5, 6, 7, 6, 7, 5, 3, 8, 9};
  static const int ACT1[22] = {0,1,2,3,4,5,6,7,8,9,10,11,13,14,15,17,18,19,20,21,23,25};
  static const int ACT2[6] = {1, 3, 5, 7, 9, 11};
  static const int AOFF[7] = {0, 50000, 52000, 132000, 142000, 144000, 294000};

  // workspace layout (floats) — total ~283.4 MB (round-3's 323.0 MB is known to fit)
  float* ws = (float*)d_ws;
  size_t offA   = 0;                                   // 414000*128 f32 (212.0MB)
  size_t offB   = offA + (size_t)414000 * HD;          // 50000*128 f32 (25.6MB)
  size_t offT   = offB + (size_t)50000 * HD;           // 150000*128 bf16 (38.4MB)
  size_t offCnt = offT + (size_t)9600000;              // 300032 ints
  size_t offRp  = offCnt + 300032;                     // 300034 ints
  size_t offCol = offRp + 300034;                      // 600000 ints
  size_t offBs  = offCol + 600000;                     // 1024 ints
  size_t offWrS = offBs + 1024;                        // 20*16384 f32
  size_t offBlS = offWrS + (size_t)20 * 16384;         // 20*128 f32
  size_t offWt  = offBlS + (size_t)20 * HD;            // 36*16384 bf16 = 294912 f32
  size_t needFloats = offWt + 294912;
  if (ws_size < needFloats * sizeof(float)) return;

  const float* x_in[10];
  for (int t = 0; t < 10; ++t) x_in[t] = (const float*)d_in[t];
  const int* ei[13];
  for (int k = 0; k < 13; ++k) ei[k] = (const int*)d_in[10 + k];
  const float* Wl   = (const float*)d_in[23];
  const float* bl   = (const float*)d_in[24];
  const float* Wr   = (const float*)d_in[25];
  const float* linW = (const float*)d_in[26];
  const float* linb = (const float*)d_in[27];
  float* out = (float*)d_out;

  unsigned short* T  = (unsigned short*)(ws + offT);
  int* cnt = (int*)(ws + offCnt);
  int* rp  = (int*)(ws + offRp);
  int* col = (int*)(ws + offCol);
  int* bs  = (int*)(ws + offBs);
  unsigned short* wt = (unsigned short*)(ws + offWt);

  auto relSrc = [&](int r) { int k = r >> 1; return (r & 1) ? FWD_D[k] : FWD_S[k]; };
  auto relDst = [&](int r) { int k = r >> 1; return (r & 1) ? FWD_S[k] : FWD_D[k]; };

  // 1. WrSum / blSum
  WSumArgs wa{};
  wa.Wr = Wr; wa.bl = bl; wa.WrSum = ws + offWrS; wa.blSum = ws + offBlS;
  for (int l = 0; l < 2; ++l)
    for (int t = 0; t < 10; ++t) wa.mask[l][t] = 0;
  for (int r = 0; r < 26; ++r) { int d = relDst(r); if (d <= 6) wa.mask[0][d] |= 1u << r; }
  for (int i = 0; i < 6; ++i) wa.mask[1][0] |= 1u << ACT2[i];
  wsum_kernel<<<1280, 256, 0, stream>>>(wa);

  // 2. weight transpose+bf16 table
  // wt slots: 0..21 = Wl layer0 ACT1; 22..27 = Wl layer1 ACT2; 28..34 = WrSum[0][0..6]; 35 = WrSum[1][0]
  WtPrepArgs wp{};
  wp.Wl = Wl; wp.WrSum = ws + offWrS; wp.wt = wt;
  for (int i = 0; i < 22; ++i) wp.code[i] = ACT1[i];
  for (int j = 0; j < 6; ++j)  wp.code[22 + j] = 26 + ACT2[j];
  for (int d = 0; d < 7; ++d)  wp.code[28 + d] = 100 + d;
  wp.code[35] = 100 + 10;
  wtprep_kernel<<<36 * 16, 256, 0, stream>>>(wp);

  auto buildPair = [&](int rA, int rB) {
    int nA = NODESN[relDst(rA)], nB = NODESN[relDst(rB)];
    int n = nA + nB;
    hipMemsetAsync(cnt, 0, (size_t)n * sizeof(int), stream);
    Build2Args ba{ei[rA >> 1], ei[rB >> 1], rA & 1, rB & 1, nA, cnt, col};
    hist2_kernel<<<(2 * EE + 255) / 256, 256, 0, stream>>>(ba);
    int nblk = (n + 2047) / 2048;
    scan_blk<<<nblk, 256, 0, stream>>>(cnt, rp, bs, n);
    scan_top<<<1, 1024, 0, stream>>>(bs, nblk);
    scan_add<<<(n + 255) / 256, 256, 0, stream>>>(rp, cnt, bs, n, 2 * EE);
    fill2_kernel<<<(2 * EE + 255) / 256, 256, 0, stream>>>(ba);
  };
  auto transGather = [&](int r, int wtIdx, int segOff, const float* xsrc, float* outd) {
    int s = relSrc(r), d = relDst(r);
    MGemmArgs g{xsrc, wt + ((size_t)wtIdx << 14), nullptr, (void*)T, NODESN[s], 1};
    mgemm_kernel<<<(NODESN[s] + 63) / 64, 256, 0, stream>>>(g);
    GatArgs ga{T, rp + segOff, col, outd, NODESN[d]};
    gather_kernel<<<(NODESN[d] + 3) / 4, 256, 0, stream>>>(ga);
  };

  // 3. layer 1 init: out = x @ WrSum + blSum for dst types 0..6
  for (int d = 0; d < 7; ++d) {
    MGemmArgs g{x_in[d], wt + ((size_t)(28 + d) << 14), ws + offBlS + (size_t)d * HD,
                (void*)(ws + offA + (size_t)AOFF[d] * HD), NODESN[d], 0};
    mgemm_kernel<<<(NODESN[d] + 63) / 64, 256, 0, stream>>>(g);
  }
  // layer 1 relations (pairs)
  for (int p = 0; p < 11; ++p) {
    int rA = ACT1[2 * p], rB = ACT1[2 * p + 1];
    buildPair(rA, rB);
    transGather(rA, 2 * p, 0, x_in[relSrc(rA)],
                ws + offA + (size_t)AOFF[relDst(rA)] * HD);
    transGather(rB, 2 * p + 1, NODESN[relDst(rA)], x_in[relSrc(rB)],
                ws + offA + (size_t)AOFF[relDst(rB)] * HD);
  }
  relu_kernel<<<(13248000 + 255) / 256, 256, 0, stream>>>((float4*)(ws + offA), 13248000);

  // 4. layer 2 (course only)
  {
    MGemmArgs g{ws + offA, wt + ((size_t)35 << 14), ws + offBlS + (size_t)10 * HD,
                (void*)(ws + offB), 50000, 0};
    mgemm_kernel<<<(50000 + 63) / 64, 256, 0, stream>>>(g);
  }
  for (int p = 0; p < 3; ++p) {
    int rA = ACT2[2 * p], rB = ACT2[2 * p + 1];
    buildPair(rA, rB);
    transGather(rA, 22 + 2 * p, 0,
                ws + offA + (size_t)AOFF[relSrc(rA)] * HD, ws + offB);
    transGather(rB, 22 + 2 * p + 1, NODESN[relDst(rA)],
                ws + offA + (size_t)AOFF[relSrc(rB)] * HD, ws + offB);
  }
  relu_kernel<<<(1600000 + 255) / 256, 256, 0, stream>>>((float4*)(ws + offB), 1600000);

  // 5. final linear
  FinalArgs fa{ws + offB, linW, linb, out, 50000};
  final_kernel<<<12500, 256, 0, stream>>>(fa);
}

// Round 8
// 2033.233 us; speedup vs baseline: 7.9614x; 1.5246x over previous
//
#include <hip/hip_runtime.h>
#include <stdint.h>

#define HD 128
#define EE 300000
#define NROWS 1528000   // sum n_dst over 22 active relations (grouped by dst)
#define NEDGE 6600000   // 22 * EE

typedef __attribute__((ext_vector_type(8))) short bf16x8;
typedef __attribute__((ext_vector_type(4))) float f32x4;
typedef __attribute__((ext_vector_type(8))) unsigned short u16x8;

static __device__ __forceinline__ unsigned short f2bf(float x) {
  union { float f; unsigned u; } v; v.f = x;
  unsigned r = v.u + 0x7FFFu + ((v.u >> 16) & 1u);
  return (unsigned short)(r >> 16);
}
static __device__ __forceinline__ float bf2f(unsigned short h) {
  union { unsigned u; float f; } v; v.u = ((unsigned)h) << 16;
  return v.f;
}

// ---------------- weight pre-sum (WrSum per (layer,type), blSum) ----------------
struct WSumArgs {
  const float* Wr;   // [2][26][128][128]
  const float* bl;   // [2][26][128]
  float* WrSum;      // [2][10][128][128]
  float* blSum;      // [2][10][128]
  unsigned int mask[2][10];
};

__global__ __launch_bounds__(256) void wsum_kernel(WSumArgs a) {
  int lt  = blockIdx.x >> 6;
  int blk = blockIdx.x & 63;
  int layer = lt / 10, type = lt % 10;
  unsigned m = a.mask[layer][type];
  int idx = blk * 256 + threadIdx.x;   // 0..16383
  float s = 0.f;
  for (int r = 0; r < 26; ++r)
    if (m & (1u << r)) s += a.Wr[((size_t)(layer * 26 + r) << 14) + idx];
  a.WrSum[((size_t)(layer * 10 + type) << 14) + idx] = s;
  if (idx < HD) {
    float b = 0.f;
    for (int r = 0; r < 26; ++r)
      if (m & (1u << r)) b += a.bl[(size_t)(layer * 26 + r) * HD + idx];
    a.blSum[(size_t)(layer * 10 + type) * HD + idx] = b;
  }
}

// ---------------- weight transpose+bf16 prep: wt[m][n][k] = bf16(src[m][k][n]) ----------------
struct WtPrepArgs {
  const float* Wl;     // [52][128][128]
  const float* WrSum;  // [20][128][128]
  unsigned short* wt;  // [36][128][128] (n-major, k contiguous)
  int code[36];        // <100: Wl flat index; >=100: WrSum flat index - 100
};

__global__ __launch_bounds__(256) void wtprep_kernel(WtPrepArgs a) {
  int m = blockIdx.x >> 4;
  int chunk = blockIdx.x & 15;
  int idx = chunk * 256 + threadIdx.x;   // float4 index 0..4095
  int c = a.code[m];
  const float* src = (c < 100) ? a.Wl + ((size_t)c << 14)
                               : a.WrSum + ((size_t)(c - 100) << 14);
  int k = idx >> 5, n0 = (idx & 31) << 2;
  float4 v = *(const float4*)(src + (size_t)k * HD + n0);
  unsigned short* d = a.wt + ((size_t)m << 14);
  d[(size_t)(n0 + 0) * HD + k] = f2bf(v.x);
  d[(size_t)(n0 + 1) * HD + k] = f2bf(v.y);
  d[(size_t)(n0 + 2) * HD + k] = f2bf(v.z);
  d[(size_t)(n0 + 3) * HD + k] = f2bf(v.w);
}

// ---------------- global CSR build over all 22 relations (grouped by dst) ----------------
struct BuildAllArgs {
  const int* ei[13];
  int* cnt;          // [NROWS] histogram, then cursor
  int* col;          // [NEDGE] src indices
  int rel[22];
  int segOff[22];    // row offset of each relation's segment
};

__global__ __launch_bounds__(256) void histall_kernel(BuildAllArgs a) {
  int i = blockIdx.x * 256 + threadIdx.x;
  if (i >= NEDGE) return;
  int ri = i / EE;
  int e  = i - ri * EE;
  int r  = a.rel[ri];
  const int* ei = a.ei[r >> 1];
  int dst = (r & 1) ? ei[e] : ei[EE + e];
  atomicAdd(&a.cnt[a.segOff[ri] + dst], 1);
}

__global__ __launch_bounds__(256) void fillall_kernel(BuildAllArgs a) {
  int i = blockIdx.x * 256 + threadIdx.x;
  if (i >= NEDGE) return;
  int ri = i / EE;
  int e  = i - ri * EE;
  int r  = a.rel[ri];
  const int* ei = a.ei[r >> 1];
  int src = (r & 1) ? ei[EE + e] : ei[e];
  int dst = (r & 1) ? ei[e] : ei[EE + e];
  int pos = atomicAdd(&a.cnt[a.segOff[ri] + dst], 1);
  a.col[pos] = src;
}

__global__ __launch_bounds__(256) void scan_blk(const int* cnt, int* rp, int* bsum, int n) {
  __shared__ int sh[256];
  int t = threadIdx.x;
  int base = blockIdx.x * 2048 + t * 8;
  int v[8]; int s = 0;
  #pragma unroll
  for (int j = 0; j < 8; ++j) { int idx = base + j; v[j] = (idx < n) ? cnt[idx] : 0; s += v[j]; }
  sh[t] = s; __syncthreads();
  for (int d = 1; d < 256; d <<= 1) {
    int x = (t >= d) ? sh[t - d] : 0;
    __syncthreads();
    sh[t] += x;
    __syncthreads();
  }
  int excl = sh[t] - s;
  if (t == 255) bsum[blockIdx.x] = sh[255];
  int run = excl;
  #pragma unroll
  for (int j = 0; j < 8; ++j) { int idx = base + j; if (idx < n) rp[idx] = run; run += v[j]; }
}

__global__ __launch_bounds__(1024) void scan_top(int* bsum, int nb) {
  __shared__ int sh[1024];
  int t = threadIdx.x;
  int s = (t < nb) ? bsum[t] : 0;
  sh[t] = s; __syncthreads();
  for (int d = 1; d < 1024; d <<= 1) {
    int x = (t >= d) ? sh[t - d] : 0;
    __syncthreads();
    sh[t] += x;
    __syncthreads();
  }
  if (t < nb) bsum[t] = sh[t] - s;
}

__global__ __launch_bounds__(256) void scan_add(int* rp, int* cur, const int* bsum, int n, int total) {
  int i = blockIdx.x * 256 + threadIdx.x;
  if (i < n) { int v = rp[i] + bsum[i >> 11]; rp[i] = v; cur[i] = v; }
  if (i == 0) rp[n] = total;
}

// ---------------- bf16 MFMA GEMM: C[M x 128] = A[M x 128] @ W[128 x 128] (+bias) ----------------
struct MGemmArgs { const void* A; const unsigned short* Wt; const float* bias; void* C;
                   int M; int outBf16; int inBf16; };

__global__ __launch_bounds__(256) void mgemm_kernel(MGemmArgs g) {
  __shared__ unsigned short As[64 * HD];   // [r][k] bf16, byte ^ ((r&7)<<4)
  __shared__ unsigned short Wsm[HD * HD];  // [n][k] bf16, byte ^ ((n&7)<<4)
  const int t = threadIdx.x;
  const int rowBase = blockIdx.x * 64;

  if (g.inBf16) {
    const unsigned short* Ab = (const unsigned short*)g.A;
    #pragma unroll
    for (int it = 0; it < 8; ++it) {
      int i4 = t + it * 256;
      int byteoff = i4 << 3;
      int r = byteoff >> 8;
      int gr = rowBase + r; if (gr >= g.M) gr = g.M - 1;
      ushort4 h = *(const ushort4*)((const char*)Ab + (size_t)gr * 256 + (byteoff & 255));
      *(ushort4*)((char*)As + (byteoff ^ ((r & 7) << 4))) = h;
    }
  } else {
    const float* Af = (const float*)g.A;
    #pragma unroll
    for (int it = 0; it < 8; ++it) {
      int f4 = t + it * 256;
      int flat = f4 << 2;
      int r = flat >> 7;
      int gr = rowBase + r; if (gr >= g.M) gr = g.M - 1;
      float4 v = *(const float4*)(Af + (size_t)gr * HD + (flat & 127));
      ushort4 h;
      h.x = f2bf(v.x); h.y = f2bf(v.y); h.z = f2bf(v.z); h.w = f2bf(v.w);
      *(ushort4*)((char*)As + ((flat << 1) ^ ((r & 7) << 4))) = h;
    }
  }
  #pragma unroll
  for (int it = 0; it < 16; ++it) {
    int i4 = t + it * 256;
    int byteoff = i4 << 3;
    int n = i4 >> 5;
    ushort4 w = *(const ushort4*)((const char*)g.Wt + byteoff);
    *(ushort4*)((char*)Wsm + (byteoff ^ ((n & 7) << 4))) = w;
  }
  __syncthreads();

  const int wv = t >> 6;
  const int lane = t & 63;
  const int lr = lane & 15;
  const int lk = lane >> 4;

  bf16x8 afr[4];
  #pragma unroll
  for (int kc = 0; kc < 4; ++kc) {
    int r = wv * 16 + lr;
    int byte = r * 256 + kc * 64 + lk * 16;
    afr[kc] = *(const bf16x8*)((char*)As + (byte ^ ((r & 7) << 4)));
  }

  f32x4 acc[8];
  #pragma unroll
  for (int nt = 0; nt < 8; ++nt) acc[nt] = (f32x4){0.f, 0.f, 0.f, 0.f};

  #pragma unroll
  for (int nt = 0; nt < 8; ++nt) {
    int n = nt * 16 + lr;
    int nbyte = n * 256 + lk * 16;
    int nswz = (n & 7) << 4;
    #pragma unroll
    for (int kc = 0; kc < 4; ++kc) {
      bf16x8 bfr = *(const bf16x8*)((char*)Wsm + ((nbyte + kc * 64) ^ nswz));
      acc[nt] = __builtin_amdgcn_mfma_f32_16x16x32_bf16(afr[kc], bfr, acc[nt], 0, 0, 0);
    }
  }

  #pragma unroll
  for (int nt = 0; nt < 8; ++nt) {
    int col = nt * 16 + lr;
    float bv = g.bias ? g.bias[col] : 0.f;
    #pragma unroll
    for (int q = 0; q < 4; ++q) {
      int grow = rowBase + wv * 16 + lk * 4 + q;
      if (grow < g.M) {
        float val = acc[nt][q] + bv;
        if (g.outBf16) ((unsigned short*)g.C)[(size_t)grow * HD + col] = f2bf(val);
        else           ((float*)g.C)[(size_t)grow * HD + col] = val;
      }
    }
  }
}

// ---------------- grouped gather: out[row] = relu(T_init[row] + sum_j mean_{src in seg_j} T_j[src]) ----------------
struct GGatArgs {
  const unsigned short* T;   // group T arena (init at rows [0,n))
  const int* rp;             // global rowptr
  const int* col;            // global col (src)
  void* outp;                // bf16 (L1) or f32 (L2)
  int n, nrel, outBf16;
  int rpOff[6];              // segment row offsets in rp
  int tOff[6];               // T row offsets per relation
};

__global__ __launch_bounds__(256) void ggather_kernel(GGatArgs g) {
  int wid  = (blockIdx.x * 256 + threadIdx.x) >> 6;
  int lane = threadIdx.x & 63;
  if (wid >= g.n) return;
  int q = lane >> 4, cl = lane & 15;       // quarter-wave q: neighbors s+q, s+q+4, ...
  float acc[8];
  #pragma unroll
  for (int k = 0; k < 8; ++k) acc[k] = 0.f;

  #pragma unroll
  for (int j = 0; j < 6; ++j) {
    if (j < g.nrel) {
      int base = g.rpOff[j] + wid;
      int s = g.rp[base], e = g.rp[base + 1];
      if (s < e) {
        float sub[8];
        #pragma unroll
        for (int k = 0; k < 8; ++k) sub[k] = 0.f;
        const unsigned short* Tj = g.T + ((size_t)g.tOff[j] << 7);
        for (int i = s + q; i < e; i += 4) {
          int src = g.col[i];
          u16x8 v = *(const u16x8*)(Tj + ((size_t)src << 7) + cl * 8);
          #pragma unroll
          for (int k = 0; k < 8; ++k) sub[k] += bf2f(v[k]);
        }
        float inv = 1.f / (float)(e - s);
        #pragma unroll
        for (int k = 0; k < 8; ++k) acc[k] += sub[k] * inv;
      }
    }
  }
  #pragma unroll
  for (int k = 0; k < 8; ++k) {
    acc[k] += __shfl_xor(acc[k], 16);
    acc[k] += __shfl_xor(acc[k], 32);
  }
  if (q == 0) {
    u16x8 iv = *(const u16x8*)(g.T + ((size_t)wid << 7) + cl * 8);
    if (g.outBf16) {
      u16x8 o;
      #pragma unroll
      for (int k = 0; k < 8; ++k) o[k] = f2bf(fmaxf(acc[k] + bf2f(iv[k]), 0.f));
      *(u16x8*)((unsigned short*)g.outp + ((size_t)wid << 7) + cl * 8) = o;
    } else {
      float* op = (float*)g.outp + ((size_t)wid << 7) + cl * 8;
      float v[8];
      #pragma unroll
      for (int k = 0; k < 8; ++k) v[k] = fmaxf(acc[k] + bf2f(iv[k]), 0.f);
      *(float4*)op       = make_float4(v[0], v[1], v[2], v[3]);
      *(float4*)(op + 4) = make_float4(v[4], v[5], v[6], v[7]);
    }
  }
}

// ---------------- final: out[M x 64] = X[M x 128] @ W[128 x 64] + b ----------------
struct FinalArgs { const float* X; const float* W; const float* b; float* out; int M; };

__global__ __launch_bounds__(256) void final_kernel(FinalArgs f) {
  __shared__ float xs[512];
  int t = threadIdx.x;
  int row0 = blockIdx.x << 2;
  {
    int li = t << 1;
    int lrow = li >> 7;
    float2 v = make_float2(0.f, 0.f);
    if (row0 + lrow < f.M) v = *(const float2*)(f.X + (size_t)(row0 + lrow) * HD + (li & 127));
    *(float2*)(&xs[li]) = v;
  }
  __syncthreads();
  int r = t >> 6, c = t & 63;
  float acc = 0.f;
  const float* xrow = &xs[r << 7];
  #pragma unroll 8
  for (int k = 0; k < HD; ++k) acc = fmaf(xrow[k], f.W[k * 64 + c], acc);
  if (row0 + r < f.M) f.out[(size_t)(row0 + r) * 64 + c] = acc + f.b[c];
}

// ---------------- host ----------------
extern "C" void kernel_launch(void* const* d_in, const int* in_sizes, int n_in,
                              void* d_out, int out_size, void* d_ws, size_t ws_size,
                              hipStream_t stream) {
  static const int NODESN[10] = {50000, 2000, 80000, 10000, 2000, 150000, 120000, 100000, 60000, 40000};
  static const int FWD_S[13] = {0, 0, 0, 0, 0, 0, 6, 5, 5, 4, 4, 2, 2};
  static const int FWD_D[13] = {1, 2, 3, 4, 5, 6, 7, 6, 7, 5, 3, 8, 9};
  static const int ACT1[22] = {0,1,2,3,4,5,6,7,8,9,10,11,13,14,15,17,18,19,20,21,23,25};
  // relations grouped by dst type (course, field, resource, teacher, school, user, comment):
  static const int GRPREL[22] = {1,3,5,7,9,11,  0,  2,23,25,  4,20,  6,19,21,  8,15,17,18,  10,13,14};
  static const int GN[7]    = {6, 1, 3, 2, 3, 4, 3};
  static const int GBASE[7] = {0, 6, 7, 10, 12, 15, 19};
  static const int AOFF[7]  = {0, 50000, 52000, 132000, 142000, 144000, 294000};

  // workspace layout (floats) — total 280.7 MB (< round-7's 283.4 MB known fit)
  float* ws = (float*)d_ws;
  size_t offA   = 0;                                   // 414000*128 bf16 = 26,496,000 f
  size_t offB   = offA + 26496000;                     // 50000*128 f32
  size_t offT   = offB + 6400000;                      // 422000*128 bf16 = 27,008,000 f
  size_t offCnt = offT + 27008000;                     // NROWS ints
  size_t offRp  = offCnt + NROWS;                      // NROWS+1 ints
  size_t offCol = offRp + NROWS + 1;                   // NEDGE ints
  size_t offBs  = offCol + NEDGE;                      // 1024 ints
  size_t offWrS = offBs + 1024;                        // 20*16384 f32
  size_t offBlS = offWrS + (size_t)20 * 16384;         // 20*128 f32
  size_t offWt  = offBlS + (size_t)20 * HD;            // 36*16384 bf16 = 294,912 f
  size_t needFloats = offWt + 294912;
  if (ws_size < needFloats * sizeof(float)) return;

  const float* x_in[10];
  for (int t = 0; t < 10; ++t) x_in[t] = (const float*)d_in[t];
  const int* ei[13];
  for (int k = 0; k < 13; ++k) ei[k] = (const int*)d_in[10 + k];
  const float* Wl   = (const float*)d_in[23];
  const float* bl   = (const float*)d_in[24];
  const float* Wr   = (const float*)d_in[25];
  const float* linW = (const float*)d_in[26];
  const float* linb = (const float*)d_in[27];
  float* out = (float*)d_out;

  unsigned short* A  = (unsigned short*)(ws + offA);
  float*          B  = ws + offB;
  unsigned short* T  = (unsigned short*)(ws + offT);
  int* cnt = (int*)(ws + offCnt);
  int* rp  = (int*)(ws + offRp);
  int* col = (int*)(ws + offCol);
  int* bs  = (int*)(ws + offBs);
  unsigned short* wt = (unsigned short*)(ws + offWt);

  auto relSrc = [&](int r) { int k = r >> 1; return (r & 1) ? FWD_D[k] : FWD_S[k]; };
  auto relDst = [&](int r) { int k = r >> 1; return (r & 1) ? FWD_S[k] : FWD_D[k]; };

  // host tables: segment row offsets (GRPREL order) and wt slots
  int segOff[22];
  { int acc = 0; for (int i = 0; i < 22; ++i) { segOff[i] = acc; acc += NODESN[relDst(GRPREL[i])]; } }
  int wtSlot[26];
  for (int r = 0; r < 26; ++r) wtSlot[r] = -1;
  for (int i = 0; i < 22; ++i) wtSlot[ACT1[i]] = i;

  // 1. WrSum / blSum
  WSumArgs wa{};
  wa.Wr = Wr; wa.bl = bl; wa.WrSum = ws + offWrS; wa.blSum = ws + offBlS;
  for (int l = 0; l < 2; ++l)
    for (int t = 0; t < 10; ++t) wa.mask[l][t] = 0;
  for (int r = 0; r < 26; ++r) { int d = relDst(r); if (d <= 6) wa.mask[0][d] |= 1u << r; }
  for (int j = 0; j < 6; ++j) wa.mask[1][0] |= 1u << GRPREL[j];
  wsum_kernel<<<1280, 256, 0, stream>>>(wa);

  // 2. weight table: slots 0..21 = Wl L0 (ACT1 order); 22..27 = Wl L1 for GRPREL[0..5];
  //    28..34 = WrSum[0][type]; 35 = WrSum[1][course]
  WtPrepArgs wp{};
  wp.Wl = Wl; wp.WrSum = ws + offWrS; wp.wt = wt;
  for (int i = 0; i < 22; ++i) wp.code[i] = ACT1[i];
  for (int j = 0; j < 6; ++j)  wp.code[22 + j] = 26 + GRPREL[j];
  for (int d = 0; d < 7; ++d)  wp.code[28 + d] = 100 + d;
  wp.code[35] = 100 + 10;
  wtprep_kernel<<<36 * 16, 256, 0, stream>>>(wp);

  // 3. global CSR build (once; L2 reuses course-group segments)
  hipMemsetAsync(cnt, 0, (size_t)NROWS * sizeof(int), stream);
  BuildAllArgs ba{};
  for (int k = 0; k < 13; ++k) ba.ei[k] = ei[k];
  ba.cnt = cnt; ba.col = col;
  for (int i = 0; i < 22; ++i) { ba.rel[i] = GRPREL[i]; ba.segOff[i] = segOff[i]; }
  histall_kernel<<<(NEDGE + 255) / 256, 256, 0, stream>>>(ba);
  int nblk = (NROWS + 2047) / 2048;   // 747
  scan_blk<<<nblk, 256, 0, stream>>>(cnt, rp, bs, NROWS);
  scan_top<<<1, 1024, 0, stream>>>(bs, nblk);
  scan_add<<<(NROWS + 255) / 256, 256, 0, stream>>>(rp, cnt, bs, NROWS, NEDGE);
  fillall_kernel<<<(NEDGE + 255) / 256, 256, 0, stream>>>(ba);

  // 4. layer 1, grouped by dst type
  for (int d = 0; d < 7; ++d) {
    int nd = NODESN[d];
    // init slot: T[0,nd) = bf16(x_d @ WrSum[0][d] + blSum)
    MGemmArgs gi{(const void*)x_in[d], wt + ((size_t)(28 + d) << 14),
                 ws + offBlS + (size_t)d * HD, (void*)T, nd, 1, 0};
    mgemm_kernel<<<(nd + 63) / 64, 256, 0, stream>>>(gi);
    GGatArgs ga{};
    ga.T = T; ga.rp = rp; ga.col = col;
    ga.outp = (void*)(A + (size_t)AOFF[d] * HD);
    ga.n = nd; ga.nrel = GN[d]; ga.outBf16 = 1;
    int toff = nd;
    for (int j = 0; j < GN[d]; ++j) {
      int r = GRPREL[GBASE[d] + j];
      int s = relSrc(r);
      MGemmArgs g{(const void*)x_in[s], wt + ((size_t)wtSlot[r] << 14), nullptr,
                  (void*)(T + (size_t)toff * HD), NODESN[s], 1, 0};
      mgemm_kernel<<<(NODESN[s] + 63) / 64, 256, 0, stream>>>(g);
      ga.rpOff[j] = segOff[GBASE[d] + j];
      ga.tOff[j] = toff;
      toff += NODESN[s];
    }
    ggather_kernel<<<(nd + 3) / 4, 256, 0, stream>>>(ga);
  }

  // 5. layer 2 (course only; same CSR segments as group 0, inputs from bf16 A)
  {
    MGemmArgs gi{(const void*)A, wt + ((size_t)35 << 14),
                 ws + offBlS + (size_t)10 * HD, (void*)T, 50000, 1, 1};
    mgemm_kernel<<<(50000 + 63) / 64, 256, 0, stream>>>(gi);
    GGatArgs ga{};
    ga.T = T; ga.rp = rp; ga.col = col;
    ga.outp = (void*)B;
    ga.n = 50000; ga.nrel = 6; ga.outBf16 = 0;
    int toff = 50000;
    for (int j = 0; j < 6; ++j) {
      int r = GRPREL[j];
      int s = relSrc(r);
      MGemmArgs g{(const void*)(A + (size_t)AOFF[s] * HD), wt + ((size_t)(22 + j) << 14),
                  nullptr, (void*)(T + (size_t)toff * HD), NODESN[s], 1, 1};
      mgemm_kernel<<<(NODESN[s] + 63) / 64, 256, 0, stream>>>(g);
      ga.rpOff[j] = segOff[j];
      ga.tOff[j] = toff;
      toff += NODESN[s];
    }
    ggather_kernel<<<(50000 + 3) / 4, 256, 0, stream>>>(ga);
  }

  // 6. final linear
  FinalArgs fa{B, linW, linb, out, 50000};
  final_kernel<<<12500, 256, 0, stream>>>(fa);
}

// Round 9
// 1507.850 us; speedup vs baseline: 10.7354x; 1.3484x over previous
//
#include <hip/hip_runtime.h>
#include <stdint.h>

#define HD 128
#define EE 300000
#define NROWS 1528000   // sum n_dst over 22 active relations (grouped by dst)
#define NEDGE 6600000   // 22 * EE
#define NB 128          // buckets per relation
#define ATILE 4096      // edges per bucketing workgroup
#define AWG 74          // ceil(EE / ATILE)

typedef __attribute__((ext_vector_type(8))) short bf16x8;
typedef __attribute__((ext_vector_type(4))) float f32x4;
typedef __attribute__((ext_vector_type(8))) unsigned short u16x8;

static __device__ __forceinline__ unsigned short f2bf(float x) {
  union { float f; unsigned u; } v; v.f = x;
  unsigned r = v.u + 0x7FFFu + ((v.u >> 16) & 1u);
  return (unsigned short)(r >> 16);
}
static __device__ __forceinline__ float bf2f(unsigned short h) {
  union { unsigned u; float f; } v; v.u = ((unsigned)h) << 16;
  return v.f;
}

// ---------------- weight pre-sum (WrSum per (layer,type), blSum) ----------------
struct WSumArgs {
  const float* Wr;   // [2][26][128][128]
  const float* bl;   // [2][26][128]
  float* WrSum;      // [2][10][128][128]
  float* blSum;      // [2][10][128]
  unsigned int mask[2][10];
};

__global__ __launch_bounds__(256) void wsum_kernel(WSumArgs a) {
  int lt  = blockIdx.x >> 6;
  int blk = blockIdx.x & 63;
  int layer = lt / 10, type = lt % 10;
  unsigned m = a.mask[layer][type];
  int idx = blk * 256 + threadIdx.x;   // 0..16383
  float s = 0.f;
  for (int r = 0; r < 26; ++r)
    if (m & (1u << r)) s += a.Wr[((size_t)(layer * 26 + r) << 14) + idx];
  a.WrSum[((size_t)(layer * 10 + type) << 14) + idx] = s;
  if (idx < HD) {
    float b = 0.f;
    for (int r = 0; r < 26; ++r)
      if (m & (1u << r)) b += a.bl[(size_t)(layer * 26 + r) * HD + idx];
    a.blSum[(size_t)(layer * 10 + type) * HD + idx] = b;
  }
}

// ---------------- weight transpose+bf16 prep: wt[m][n][k] = bf16(src[m][k][n]) ----------------
struct WtPrepArgs {
  const float* Wl;     // [52][128][128]
  const float* WrSum;  // [20][128][128]
  unsigned short* wt;  // [36][128][128] (n-major, k contiguous)
  int code[36];        // <100: Wl flat index; >=100: WrSum flat index - 100
};

__global__ __launch_bounds__(256) void wtprep_kernel(WtPrepArgs a) {
  int m = blockIdx.x >> 4;
  int chunk = blockIdx.x & 15;
  int idx = chunk * 256 + threadIdx.x;   // float4 index 0..4095
  int c = a.code[m];
  const float* src = (c < 100) ? a.Wl + ((size_t)c << 14)
                               : a.WrSum + ((size_t)(c - 100) << 14);
  int k = idx >> 5, n0 = (idx & 31) << 2;
  float4 v = *(const float4*)(src + (size_t)k * HD + n0);
  unsigned short* d = a.wt + ((size_t)m << 14);
  d[(size_t)(n0 + 0) * HD + k] = f2bf(v.x);
  d[(size_t)(n0 + 1) * HD + k] = f2bf(v.y);
  d[(size_t)(n0 + 2) * HD + k] = f2bf(v.z);
  d[(size_t)(n0 + 3) * HD + k] = f2bf(v.w);
}

// ---------------- bucketed CSR build ----------------
// Phase A: bucket edges of each relation by dst>>shift into <=128 compact buckets,
// entries packed as (dstlow<<18)|src. Phase B: per-bucket row counts (coalesced) and
// final placement (bucket-local scattered writes -> single-wg cache locality).
struct BktArgs {
  const int* ei[13];
  unsigned* bkt;     // [NEDGE] packed entries
  int* bktCnt;       // [22*NB] bucket sizes (A0 out)
  int* bktCur;       // [22*NB] cursors seeded with bucket bases (A1)
  int rel[22];
  int shiftv[22];
};

__global__ __launch_bounds__(256) void bktcount_kernel(BktArgs a) {
  __shared__ int cnt[NB];
  int ri = blockIdx.x / AWG;
  int tile = (blockIdx.x % AWG) * ATILE;
  int t = threadIdx.x;
  if (t < NB) cnt[t] = 0;
  __syncthreads();
  int r = a.rel[ri];
  const int* ei = a.ei[r >> 1];
  int flip = r & 1, sh = a.shiftv[ri];
  #pragma unroll
  for (int j = 0; j < 16; ++j) {
    int e = tile + j * 256 + t;
    if (e < EE) {
      int dst = flip ? ei[e] : ei[EE + e];
      atomicAdd(&cnt[dst >> sh], 1);
    }
  }
  __syncthreads();
  if (t < NB && cnt[t]) atomicAdd(&a.bktCnt[ri * NB + t], cnt[t]);
}

__global__ __launch_bounds__(256) void bktfill_kernel(BktArgs a) {
  __shared__ int cnt[NB];
  __shared__ int base[NB];
  int ri = blockIdx.x / AWG;
  int tile = (blockIdx.x % AWG) * ATILE;
  int t = threadIdx.x;
  if (t < NB) cnt[t] = 0;
  __syncthreads();
  int r = a.rel[ri];
  const int* ei = a.ei[r >> 1];
  int flip = r & 1, sh = a.shiftv[ri];
  unsigned mask = (1u << sh) - 1u;
  unsigned pj[16]; int bj[16];
  #pragma unroll
  for (int j = 0; j < 16; ++j) {
    int e = tile + j * 256 + t;
    if (e < EE) {
      int src = flip ? ei[EE + e] : ei[e];
      int dst = flip ? ei[e] : ei[EE + e];
      int b = dst >> sh;
      pj[j] = (((unsigned)dst & mask) << 18) | (unsigned)src;
      bj[j] = b;
      atomicAdd(&cnt[b], 1);
    } else bj[j] = -1;
  }
  __syncthreads();
  if (t < NB) base[t] = cnt[t] ? atomicAdd(&a.bktCur[ri * NB + t], cnt[t]) : 0;
  __syncthreads();
  if (t < NB) cnt[t] = base[t];
  __syncthreads();
  #pragma unroll
  for (int j = 0; j < 16; ++j) {
    if (bj[j] >= 0) {
      int pos = atomicAdd(&cnt[bj[j]], 1);
      a.bkt[pos] = pj[j];
    }
  }
}

struct PlaceArgs {
  const unsigned* bkt;
  const int* bktRp;   // [22*NB+1] bucket bases
  int* cntG;          // [NROWS] row counts out (B1)
  const int* rp;      // [NROWS+1] rowptr in (B2)
  int* col;           // [NEDGE] out (B2)
  int segOff[22];
  int shiftv[22];
  int nDst[22];
};

__global__ __launch_bounds__(256) void rowcount_kernel(PlaceArgs a) {
  __shared__ int cnt[2048];
  int bx = blockIdx.x;
  int ri = bx >> 7, b = bx & (NB - 1);
  int sh = a.shiftv[ri], nd = a.nDst[ri];
  int rowLo = b << sh;
  if (rowLo >= nd) return;
  int rows = min(1 << sh, nd - rowLo);
  int t = threadIdx.x;
  for (int k = t; k < rows; k += 256) cnt[k] = 0;
  __syncthreads();
  int s = a.bktRp[bx], e = a.bktRp[bx + 1];
  for (int i = s + t; i < e; i += 256) atomicAdd(&cnt[a.bkt[i] >> 18], 1);
  __syncthreads();
  int rowBase = a.segOff[ri] + rowLo;
  for (int k = t; k < rows; k += 256) a.cntG[rowBase + k] = cnt[k];
}

__global__ __launch_bounds__(256) void place_kernel(PlaceArgs a) {
  __shared__ int cur[2048];
  int bx = blockIdx.x;
  int ri = bx >> 7, b = bx & (NB - 1);
  int sh = a.shiftv[ri], nd = a.nDst[ri];
  int rowLo = b << sh;
  if (rowLo >= nd) return;
  int rows = min(1 << sh, nd - rowLo);
  int t = threadIdx.x;
  int rowBase = a.segOff[ri] + rowLo;
  for (int k = t; k < rows; k += 256) cur[k] = a.rp[rowBase + k];
  __syncthreads();
  int s = a.bktRp[bx], e = a.bktRp[bx + 1];
  for (int i = s + t; i < e; i += 256) {
    unsigned u = a.bkt[i];
    int pos = atomicAdd(&cur[u >> 18], 1);
    a.col[pos] = (int)(u & 0x3FFFFu);
  }
}

// ---------------- scans (shared by bucket-base scan and row scan) ----------------
__global__ __launch_bounds__(256) void scan_blk(const int* cnt, int* rp, int* bsum, int n) {
  __shared__ int sh[256];
  int t = threadIdx.x;
  int base = blockIdx.x * 2048 + t * 8;
  int v[8]; int s = 0;
  #pragma unroll
  for (int j = 0; j < 8; ++j) { int idx = base + j; v[j] = (idx < n) ? cnt[idx] : 0; s += v[j]; }
  sh[t] = s; __syncthreads();
  for (int d = 1; d < 256; d <<= 1) {
    int x = (t >= d) ? sh[t - d] : 0;
    __syncthreads();
    sh[t] += x;
    __syncthreads();
  }
  int excl = sh[t] - s;
  if (t == 255) bsum[blockIdx.x] = sh[255];
  int run = excl;
  #pragma unroll
  for (int j = 0; j < 8; ++j) { int idx = base + j; if (idx < n) rp[idx] = run; run += v[j]; }
}

__global__ __launch_bounds__(1024) void scan_top(int* bsum, int nb) {
  __shared__ int sh[1024];
  int t = threadIdx.x;
  int s = (t < nb) ? bsum[t] : 0;
  sh[t] = s; __syncthreads();
  for (int d = 1; d < 1024; d <<= 1) {
    int x = (t >= d) ? sh[t - d] : 0;
    __syncthreads();
    sh[t] += x;
    __syncthreads();
  }
  if (t < nb) bsum[t] = sh[t] - s;
}

__global__ __launch_bounds__(256) void scan_add(int* rp, int* cur, const int* bsum, int n, int total) {
  int i = blockIdx.x * 256 + threadIdx.x;
  if (i < n) { int v = rp[i] + bsum[i >> 11]; rp[i] = v; cur[i] = v; }
  if (i == 0) rp[n] = total;
}

// ---------------- bf16 MFMA GEMM: C[M x 128] = A[M x 128] @ W[128 x 128] (+bias) ----------------
struct MGemmArgs { const void* A; const unsigned short* Wt; const float* bias; void* C;
                   int M; int outBf16; int inBf16; };

__global__ __launch_bounds__(256) void mgemm_kernel(MGemmArgs g) {
  __shared__ unsigned short As[64 * HD];   // [r][k] bf16, byte ^ ((r&7)<<4)
  __shared__ unsigned short Wsm[HD * HD];  // [n][k] bf16, byte ^ ((n&7)<<4)
  const int t = threadIdx.x;
  const int rowBase = blockIdx.x * 64;

  if (g.inBf16) {
    const unsigned short* Ab = (const unsigned short*)g.A;
    #pragma unroll
    for (int it = 0; it < 8; ++it) {
      int i4 = t + it * 256;
      int byteoff = i4 << 3;
      int r = byteoff >> 8;
      int gr = rowBase + r; if (gr >= g.M) gr = g.M - 1;
      ushort4 h = *(const ushort4*)((const char*)Ab + (size_t)gr * 256 + (byteoff & 255));
      *(ushort4*)((char*)As + (byteoff ^ ((r & 7) << 4))) = h;
    }
  } else {
    const float* Af = (const float*)g.A;
    #pragma unroll
    for (int it = 0; it < 8; ++it) {
      int f4 = t + it * 256;
      int flat = f4 << 2;
      int r = flat >> 7;
      int gr = rowBase + r; if (gr >= g.M) gr = g.M - 1;
      float4 v = *(const float4*)(Af + (size_t)gr * HD + (flat & 127));
      ushort4 h;
      h.x = f2bf(v.x); h.y = f2bf(v.y); h.z = f2bf(v.z); h.w = f2bf(v.w);
      *(ushort4*)((char*)As + ((flat << 1) ^ ((r & 7) << 4))) = h;
    }
  }
  #pragma unroll
  for (int it = 0; it < 16; ++it) {
    int i4 = t + it * 256;
    int byteoff = i4 << 3;
    int n = i4 >> 5;
    ushort4 w = *(const ushort4*)((const char*)g.Wt + byteoff);
    *(ushort4*)((char*)Wsm + (byteoff ^ ((n & 7) << 4))) = w;
  }
  __syncthreads();

  const int wv = t >> 6;
  const int lane = t & 63;
  const int lr = lane & 15;
  const int lk = lane >> 4;

  bf16x8 afr[4];
  #pragma unroll
  for (int kc = 0; kc < 4; ++kc) {
    int r = wv * 16 + lr;
    int byte = r * 256 + kc * 64 + lk * 16;
    afr[kc] = *(const bf16x8*)((char*)As + (byte ^ ((r & 7) << 4)));
  }

  f32x4 acc[8];
  #pragma unroll
  for (int nt = 0; nt < 8; ++nt) acc[nt] = (f32x4){0.f, 0.f, 0.f, 0.f};

  #pragma unroll
  for (int nt = 0; nt < 8; ++nt) {
    int n = nt * 16 + lr;
    int nbyte = n * 256 + lk * 16;
    int nswz = (n & 7) << 4;
    #pragma unroll
    for (int kc = 0; kc < 4; ++kc) {
      bf16x8 bfr = *(const bf16x8*)((char*)Wsm + ((nbyte + kc * 64) ^ nswz));
      acc[nt] = __builtin_amdgcn_mfma_f32_16x16x32_bf16(afr[kc], bfr, acc[nt], 0, 0, 0);
    }
  }

  #pragma unroll
  for (int nt = 0; nt < 8; ++nt) {
    int col = nt * 16 + lr;
    float bv = g.bias ? g.bias[col] : 0.f;
    #pragma unroll
    for (int q = 0; q < 4; ++q) {
      int grow = rowBase + wv * 16 + lk * 4 + q;
      if (grow < g.M) {
        float val = acc[nt][q] + bv;
        if (g.outBf16) ((unsigned short*)g.C)[(size_t)grow * HD + col] = f2bf(val);
        else           ((float*)g.C)[(size_t)grow * HD + col] = val;
      }
    }
  }
}

// ---------------- grouped gather: out[row] = relu(T_init[row] + sum_j mean_{src in seg_j} T_j[src]) ----------------
struct GGatArgs {
  const unsigned short* T;   // group T arena (init at rows [0,n))
  const int* rp;             // global rowptr
  const int* col;            // global col (src)
  void* outp;                // bf16 (L1) or f32 (L2)
  int n, nrel, outBf16;
  int rpOff[6];              // segment row offsets in rp
  int tOff[6];               // T row offsets per relation
};

__global__ __launch_bounds__(256) void ggather_kernel(GGatArgs g) {
  int wid  = (blockIdx.x * 256 + threadIdx.x) >> 6;
  int lane = threadIdx.x & 63;
  if (wid >= g.n) return;
  int q = lane >> 4, cl = lane & 15;       // quarter-wave q: neighbors s+q, s+q+4, ...
  float acc[8];
  #pragma unroll
  for (int k = 0; k < 8; ++k) acc[k] = 0.f;

  #pragma unroll
  for (int j = 0; j < 6; ++j) {
    if (j < g.nrel) {
      int base = g.rpOff[j] + wid;
      int s = g.rp[base], e = g.rp[base + 1];
      if (s < e) {
        float sub[8];
        #pragma unroll
        for (int k = 0; k < 8; ++k) sub[k] = 0.f;
        const unsigned short* Tj = g.T + ((size_t)g.tOff[j] << 7);
        for (int i = s + q; i < e; i += 4) {
          int src = g.col[i];
          u16x8 v = *(const u16x8*)(Tj + ((size_t)src << 7) + cl * 8);
          #pragma unroll
          for (int k = 0; k < 8; ++k) sub[k] += bf2f(v[k]);
        }
        float inv = 1.f / (float)(e - s);
        #pragma unroll
        for (int k = 0; k < 8; ++k) acc[k] += sub[k] * inv;
      }
    }
  }
  #pragma unroll
  for (int k = 0; k < 8; ++k) {
    acc[k] += __shfl_xor(acc[k], 16);
    acc[k] += __shfl_xor(acc[k], 32);
  }
  if (q == 0) {
    u16x8 iv = *(const u16x8*)(g.T + ((size_t)wid << 7) + cl * 8);
    if (g.outBf16) {
      u16x8 o;
      #pragma unroll
      for (int k = 0; k < 8; ++k) o[k] = f2bf(fmaxf(acc[k] + bf2f(iv[k]), 0.f));
      *(u16x8*)((unsigned short*)g.outp + ((size_t)wid << 7) + cl * 8) = o;
    } else {
      float* op = (float*)g.outp + ((size_t)wid << 7) + cl * 8;
      float v[8];
      #pragma unroll
      for (int k = 0; k < 8; ++k) v[k] = fmaxf(acc[k] + bf2f(iv[k]), 0.f);
      *(float4*)op       = make_float4(v[0], v[1], v[2], v[3]);
      *(float4*)(op + 4) = make_float4(v[4], v[5], v[6], v[7]);
    }
  }
}

// ---------------- final: out[M x 64] = X[M x 128] @ W[128 x 64] + b ----------------
struct FinalArgs { const float* X; const float* W; const float* b; float* out; int M; };

__global__ __launch_bounds__(256) void final_kernel(FinalArgs f) {
  __shared__ float xs[512];
  int t = threadIdx.x;
  int row0 = blockIdx.x << 2;
  {
    int li = t << 1;
    int lrow = li >> 7;
    float2 v = make_float2(0.f, 0.f);
    if (row0 + lrow < f.M) v = *(const float2*)(f.X + (size_t)(row0 + lrow) * HD + (li & 127));
    *(float2*)(&xs[li]) = v;
  }
  __syncthreads();
  int r = t >> 6, c = t & 63;
  float acc = 0.f;
  const float* xrow = &xs[r << 7];
  #pragma unroll 8
  for (int k = 0; k < HD; ++k) acc = fmaf(xrow[k], f.W[k * 64 + c], acc);
  if (row0 + r < f.M) f.out[(size_t)(row0 + r) * 64 + c] = acc + f.b[c];
}

// ---------------- host ----------------
extern "C" void kernel_launch(void* const* d_in, const int* in_sizes, int n_in,
                              void* d_out, int out_size, void* d_ws, size_t ws_size,
                              hipStream_t stream) {
  static const int NODESN[10] = {50000, 2000, 80000, 10000, 2000, 150000, 120000, 100000, 60000, 40000};
  static const int FWD_S[13] = {0, 0, 0, 0, 0, 0, 6, 5, 5, 4, 4, 2, 2};
  static const int FWD_D[13] = {1, 2, 3, 4, 5, 6, 7, 6, 7, 5, 3, 8, 9};
  static const int ACT1[22] = {0,1,2,3,4,5,6,7,8,9,10,11,13,14,15,17,18,19,20,21,23,25};
  // relations grouped by dst type (course, field, resource, teacher, school, user, comment):
  static const int GRPREL[22] = {1,3,5,7,9,11,  0,  2,23,25,  4,20,  6,19,21,  8,15,17,18,  10,13,14};
  static const int GN[7]    = {6, 1, 3, 2, 3, 4, 3};
  static const int GBASE[7] = {0, 6, 7, 10, 12, 15, 19};
  static const int AOFF[7]  = {0, 50000, 52000, 132000, 142000, 144000, 294000};

  // workspace layout (floats) — total ~307.2 MB (< round-3's 323.0 MB known fit)
  float* ws = (float*)d_ws;
  size_t offA    = 0;                                  // 414000*128 bf16 = 26,496,000 f
  size_t offB    = offA + 26496000;                    // 50000*128 f32
  size_t offT    = offB + 6400000;                     // 422000*128 bf16 = 27,008,000 f
  size_t offCnt  = offT + 27008000;                    // NROWS ints
  size_t offRp   = offCnt + NROWS;                     // NROWS+1 ints
  size_t offCol  = offRp + NROWS + 1;                  // NEDGE ints
  size_t offBkt  = offCol + NEDGE;                     // NEDGE u32
  size_t offBCnt = offBkt + NEDGE;                     // 22*NB ints
  size_t offBRp  = offBCnt + 22 * NB;                  // 22*NB+1 ints
  size_t offBCur = offBRp + 22 * NB + 4;               // 22*NB ints
  size_t offBs   = offBCur + 22 * NB;                  // 1024 ints
  size_t offWrS  = offBs + 1024;                       // 20*16384 f32
  size_t offBlS  = offWrS + (size_t)20 * 16384;        // 20*128 f32
  size_t offWt   = offBlS + (size_t)20 * HD;           // 36*16384 bf16 = 294,912 f
  size_t needFloats = offWt + 294912;
  if (ws_size < needFloats * sizeof(float)) return;

  const float* x_in[10];
  for (int t = 0; t < 10; ++t) x_in[t] = (const float*)d_in[t];
  const int* ei[13];
  for (int k = 0; k < 13; ++k) ei[k] = (const int*)d_in[10 + k];
  const float* Wl   = (const float*)d_in[23];
  const float* bl   = (const float*)d_in[24];
  const float* Wr   = (const float*)d_in[25];
  const float* linW = (const float*)d_in[26];
  const float* linb = (const float*)d_in[27];
  float* out = (float*)d_out;

  unsigned short* A  = (unsigned short*)(ws + offA);
  float*          B  = ws + offB;
  unsigned short* T  = (unsigned short*)(ws + offT);
  int* cnt  = (int*)(ws + offCnt);
  int* rp   = (int*)(ws + offRp);
  int* col  = (int*)(ws + offCol);
  unsigned* bkt = (unsigned*)(ws + offBkt);
  int* bCnt = (int*)(ws + offBCnt);
  int* bRp  = (int*)(ws + offBRp);
  int* bCur = (int*)(ws + offBCur);
  int* bs   = (int*)(ws + offBs);
  unsigned short* wt = (unsigned short*)(ws + offWt);

  auto relSrc = [&](int r) { int k = r >> 1; return (r & 1) ? FWD_D[k] : FWD_S[k]; };
  auto relDst = [&](int r) { int k = r >> 1; return (r & 1) ? FWD_S[k] : FWD_D[k]; };

  // host tables
  int segOff[22], shiftv[22], nDstv[22];
  { int acc = 0;
    for (int i = 0; i < 22; ++i) {
      int nd = NODESN[relDst(GRPREL[i])];
      segOff[i] = acc; acc += nd;
      nDstv[i] = nd;
      int s = 0; while (((nd + (1 << s) - 1) >> s) > NB) ++s;
      shiftv[i] = s;
    }
  }
  int wtSlot[26];
  for (int r = 0; r < 26; ++r) wtSlot[r] = -1;
  for (int i = 0; i < 22; ++i) wtSlot[ACT1[i]] = i;

  // 1. WrSum / blSum
  WSumArgs wa{};
  wa.Wr = Wr; wa.bl = bl; wa.WrSum = ws + offWrS; wa.blSum = ws + offBlS;
  for (int l = 0; l < 2; ++l)
    for (int t = 0; t < 10; ++t) wa.mask[l][t] = 0;
  for (int r = 0; r < 26; ++r) { int d = relDst(r); if (d <= 6) wa.mask[0][d] |= 1u << r; }
  for (int j = 0; j < 6; ++j) wa.mask[1][0] |= 1u << GRPREL[j];
  wsum_kernel<<<1280, 256, 0, stream>>>(wa);

  // 2. weight table
  WtPrepArgs wp{};
  wp.Wl = Wl; wp.WrSum = ws + offWrS; wp.wt = wt;
  for (int i = 0; i < 22; ++i) wp.code[i] = ACT1[i];
  for (int j = 0; j < 6; ++j)  wp.code[22 + j] = 26 + GRPREL[j];
  for (int d = 0; d < 7; ++d)  wp.code[28 + d] = 100 + d;
  wp.code[35] = 100 + 10;
  wtprep_kernel<<<36 * 16, 256, 0, stream>>>(wp);

  // 3. bucketed CSR build
  hipMemsetAsync(bCnt, 0, (size_t)22 * NB * sizeof(int), stream);
  BktArgs ka{};
  for (int k = 0; k < 13; ++k) ka.ei[k] = ei[k];
  ka.bkt = bkt; ka.bktCnt = bCnt; ka.bktCur = bCur;
  for (int i = 0; i < 22; ++i) { ka.rel[i] = GRPREL[i]; ka.shiftv[i] = shiftv[i]; }
  bktcount_kernel<<<22 * AWG, 256, 0, stream>>>(ka);
  scan_blk<<<2, 256, 0, stream>>>(bCnt, bRp, bs, 22 * NB);
  scan_top<<<1, 1024, 0, stream>>>(bs, 2);
  scan_add<<<(22 * NB + 255) / 256, 256, 0, stream>>>(bRp, bCur, bs, 22 * NB, NEDGE);
  bktfill_kernel<<<22 * AWG, 256, 0, stream>>>(ka);
  PlaceArgs pa{};
  pa.bkt = bkt; pa.bktRp = bRp; pa.cntG = cnt; pa.rp = rp; pa.col = col;
  for (int i = 0; i < 22; ++i) { pa.segOff[i] = segOff[i]; pa.shiftv[i] = shiftv[i]; pa.nDst[i] = nDstv[i]; }
  rowcount_kernel<<<22 * NB, 256, 0, stream>>>(pa);
  int nblk = (NROWS + 2047) / 2048;   // 747
  scan_blk<<<nblk, 256, 0, stream>>>(cnt, rp, bs, NROWS);
  scan_top<<<1, 1024, 0, stream>>>(bs, nblk);
  scan_add<<<(NROWS + 255) / 256, 256, 0, stream>>>(rp, cnt, bs, NROWS, NEDGE);
  place_kernel<<<22 * NB, 256, 0, stream>>>(pa);

  // 4. layer 1, grouped by dst type
  for (int d = 0; d < 7; ++d) {
    int nd = NODESN[d];
    MGemmArgs gi{(const void*)x_in[d], wt + ((size_t)(28 + d) << 14),
                 ws + offBlS + (size_t)d * HD, (void*)T, nd, 1, 0};
    mgemm_kernel<<<(nd + 63) / 64, 256, 0, stream>>>(gi);
    GGatArgs ga{};
    ga.T = T; ga.rp = rp; ga.col = col;
    ga.outp = (void*)(A + (size_t)AOFF[d] * HD);
    ga.n = nd; ga.nrel = GN[d]; ga.outBf16 = 1;
    int toff = nd;
    for (int j = 0; j < GN[d]; ++j) {
      int r = GRPREL[GBASE[d] + j];
      int s = relSrc(r);
      MGemmArgs g{(const void*)x_in[s], wt + ((size_t)wtSlot[r] << 14), nullptr,
                  (void*)(T + (size_t)toff * HD), NODESN[s], 1, 0};
      mgemm_kernel<<<(NODESN[s] + 63) / 64, 256, 0, stream>>>(g);
      ga.rpOff[j] = segOff[GBASE[d] + j];
      ga.tOff[j] = toff;
      toff += NODESN[s];
    }
    ggather_kernel<<<(nd + 3) / 4, 256, 0, stream>>>(ga);
  }

  // 5. layer 2 (course only; same CSR segments as group 0, inputs from bf16 A)
  {
    MGemmArgs gi{(const void*)A, wt + ((size_t)35 << 14),
                 ws + offBlS + (size_t)10 * HD, (void*)T, 50000, 1, 1};
    mgemm_kernel<<<(50000 + 63) / 64, 256, 0, stream>>>(gi);
    GGatArgs ga{};
    ga.T = T; ga.rp = rp; ga.col = col;
    ga.outp = (void*)B;
    ga.n = 50000; ga.nrel = 6; ga.outBf16 = 0;
    int toff = 50000;
    for (int j = 0; j < 6; ++j) {
      int r = GRPREL[j];
      int s = relSrc(r);
      MGemmArgs g{(const void*)(A + (size_t)AOFF[s] * HD), wt + ((size_t)(22 + j) << 14),
                  nullptr, (void*)(T + (size_t)toff * HD), NODESN[s], 1, 1};
      mgemm_kernel<<<(NODESN[s] + 63) / 64, 256, 0, stream>>>(g);
      ga.rpOff[j] = segOff[j];
      ga.tOff[j] = toff;
      toff += NODESN[s];
    }
    ggather_kernel<<<(50000 + 3) / 4, 256, 0, stream>>>(ga);
  }

  // 6. final linear
  FinalArgs fa{B, linW, linb, out, 50000};
  final_kernel<<<12500, 256, 0, stream>>>(fa);
}